// Round 1
// baseline (2224.760 us; speedup 1.0000x reference)
//
#include <hip/hip_runtime.h>
#include <math.h>

#define D 64
#define NH 4
#define DH 16
#define NB 64

// ---------------------------------------------------------------------------
// Scatter-add aggregation for SAGE mean: agg[dst] += x[src], cnt[dst] += 1
// edge layout [2, E]: row 0 = src, row 1 = dst
// ---------------------------------------------------------------------------
__global__ void k_agg(const float* __restrict__ x, const int* __restrict__ edge,
                      int E, int logF, float* __restrict__ agg, float* __restrict__ cnt) {
    int F = 1 << logF;
    long total = (long)E << logF;
    long stride = (long)gridDim.x * blockDim.x;
    for (long i = (long)blockIdx.x * blockDim.x + threadIdx.x; i < total; i += stride) {
        int e = (int)(i >> logF);
        int f = (int)(i & (F - 1));
        int s = edge[e];
        int d = edge[E + e];
        atomicAdd(&agg[(long)d * F + f], x[(long)s * F + f]);
        if (f == 0) atomicAdd(&cnt[d], 1.0f);
    }
}

// ---------------------------------------------------------------------------
// SAGE linear: out = relu((agg/max(cnt,1)) @ wl + bl + x @ wr)
// wl, wr: [FIN, 64]
// ---------------------------------------------------------------------------
template<int FIN>
__global__ void k_sage(const float* __restrict__ x, const float* __restrict__ agg,
                       const float* __restrict__ cnt, int N,
                       const float* __restrict__ wl, const float* __restrict__ bl,
                       const float* __restrict__ wr, float* __restrict__ out) {
    __shared__ float swl[FIN * D];
    __shared__ float swr[FIN * D];
    for (int i = threadIdx.x; i < FIN * D; i += blockDim.x) { swl[i] = wl[i]; swr[i] = wr[i]; }
    __syncthreads();
    const int rpb = 4;  // 256 threads / 64 cols
    int c = threadIdx.x & 63;
    for (int r = blockIdx.x * rpb + (threadIdx.x >> 6); r < N; r += gridDim.x * rpb) {
        float inv = 1.0f / fmaxf(cnt[r], 1.0f);
        float acc = bl[c];
        #pragma unroll 8
        for (int k = 0; k < FIN; ++k) {
            acc += agg[r * FIN + k] * inv * swl[k * D + c];
            acc += x[r * FIN + k] * swr[k * D + c];
        }
        out[r * D + c] = fmaxf(acc, 0.0f);
    }
}

// ---------------------------------------------------------------------------
// Plain linear: out = x @ w + b   (x: [N,64], w: [64,64], b: [64])
// ---------------------------------------------------------------------------
__global__ void k_linear(const float* __restrict__ x, int N,
                         const float* __restrict__ w, const float* __restrict__ b,
                         float* __restrict__ out) {
    __shared__ float sw[D * D];
    for (int i = threadIdx.x; i < D * D; i += blockDim.x) sw[i] = w[i];
    __syncthreads();
    int r = blockIdx.x * 4 + (threadIdx.x >> 6);
    int c = threadIdx.x & 63;
    if (r >= N) return;
    float acc = b[c];
    #pragma unroll 8
    for (int k = 0; k < D; ++k) acc += x[r * D + k] * sw[k * D + c];
    out[r * D + c] = acc;
}

// ---------------------------------------------------------------------------
// Cross-attention, one wave per (query, head), online softmax over all keys.
// out[q, h*16+j] = resid[q, h*16+j] + sum_k softmax_k(Q.K/4) V[k, h*16+j]
// ---------------------------------------------------------------------------
__global__ void k_attn(const float* __restrict__ Q, const float* __restrict__ K,
                       const float* __restrict__ V, int Nq, int Nk,
                       const float* __restrict__ resid, float* __restrict__ out) {
    int wid = (blockIdx.x * blockDim.x + threadIdx.x) >> 6;
    int lane = threadIdx.x & 63;
    if (wid >= Nq * NH) return;
    int q = wid >> 2;
    int h = wid & 3;
    const float scale = 0.25f;  // 1/sqrt(DH)

    float qv[DH];
    #pragma unroll
    for (int j = 0; j < DH; ++j) qv[j] = Q[q * D + h * DH + j] * scale;

    float m = -1e30f, l = 0.0f;
    float acc[DH];
    #pragma unroll
    for (int j = 0; j < DH; ++j) acc[j] = 0.0f;

    for (int k = lane; k < Nk; k += 64) {
        const float* kr = K + (long)k * D + h * DH;
        float s = 0.0f;
        #pragma unroll
        for (int j = 0; j < DH; ++j) s += qv[j] * kr[j];
        const float* vr = V + (long)k * D + h * DH;
        if (s <= m) {
            float e = __expf(s - m);
            l += e;
            #pragma unroll
            for (int j = 0; j < DH; ++j) acc[j] += e * vr[j];
        } else {
            float sc = __expf(m - s);
            l = l * sc + 1.0f;
            #pragma unroll
            for (int j = 0; j < DH; ++j) acc[j] = acc[j] * sc + vr[j];
            m = s;
        }
    }

    // butterfly combine of (m, l, acc[16]) across 64 lanes
    #pragma unroll
    for (int off = 32; off > 0; off >>= 1) {
        float mo = __shfl_xor(m, off);
        float lo = __shfl_xor(l, off);
        float M = fmaxf(m, mo);
        float a = __expf(m - M);
        float bsc = __expf(mo - M);
        l = l * a + lo * bsc;
        #pragma unroll
        for (int j = 0; j < DH; ++j) {
            float ao = __shfl_xor(acc[j], off);
            acc[j] = acc[j] * a + ao * bsc;
        }
        m = M;
    }
    float invl = 1.0f / l;
    float val = 0.0f;
    #pragma unroll
    for (int j = 0; j < DH; ++j) if (lane == j) val = acc[j];
    if (lane < DH) {
        int idx = q * D + h * DH + lane;
        out[idx] = resid[idx] + val * invl;
    }
}

// ---------------------------------------------------------------------------
// Segment-sum pooling: zsum[batch[n], colOff + c] += h[n, c]; zcnt counts nodes
// ---------------------------------------------------------------------------
__global__ void k_pool(const float* __restrict__ h, const int* __restrict__ batch,
                       int N, int colOff, float* __restrict__ zsum, float* __restrict__ zcnt) {
    int idx = blockIdx.x * blockDim.x + threadIdx.x;
    if (idx >= N * D) return;
    int n = idx >> 6;
    int c = idx & 63;
    int b = batch[n];
    atomicAdd(&zsum[b * 128 + colOff + c], h[idx]);
    if (c == 0) atomicAdd(&zcnt[b * 2 + (colOff ? 1 : 0)], 1.0f);
}

// ---------------------------------------------------------------------------
// Head: z = zsum/cnt -> relu(z @ fc1 + b1) -> sigmoid(x @ fc2 + b2)
// single block, 256 threads
// ---------------------------------------------------------------------------
__global__ void k_head(const float* __restrict__ zsum, const float* __restrict__ zcnt,
                       const float* __restrict__ fc1w, const float* __restrict__ fc1b,
                       const float* __restrict__ fc2w, const float* __restrict__ fc2b,
                       float* __restrict__ out) {
    __shared__ float z[NB * 128];
    __shared__ float x1[NB * D];
    int t = threadIdx.x;
    for (int i = t; i < NB * 128; i += blockDim.x) {
        int b = i >> 7;
        int c = i & 127;
        float cn = zcnt[b * 2 + (c >> 6)];
        z[i] = zsum[i] / fmaxf(cn, 1.0f);
    }
    __syncthreads();
    for (int i = t; i < NB * D; i += blockDim.x) {
        int b = i >> 6;
        int c = i & 63;
        float acc = fc1b[c];
        #pragma unroll 8
        for (int k = 0; k < 128; ++k) acc += z[b * 128 + k] * fc1w[k * D + c];
        x1[i] = fmaxf(acc, 0.0f);
    }
    __syncthreads();
    if (t < NB) {
        float acc = fc2b[0];
        #pragma unroll 8
        for (int c = 0; c < D; ++c) acc += x1[t * D + c] * fc2w[c];
        out[t] = 1.0f / (1.0f + __expf(-acc));
    }
}

// ---------------------------------------------------------------------------
extern "C" void kernel_launch(void* const* d_in, const int* in_sizes, int n_in,
                              void* d_out, int out_size, void* d_ws, size_t ws_size,
                              hipStream_t stream) {
    const float* x_mol  = (const float*)d_in[0];
    const float* x_prot = (const float*)d_in[1];
    const float* m1_wl = (const float*)d_in[2];
    const float* m1_bl = (const float*)d_in[3];
    const float* m1_wr = (const float*)d_in[4];
    const float* m2_wl = (const float*)d_in[5];
    const float* m2_bl = (const float*)d_in[6];
    const float* m2_wr = (const float*)d_in[7];
    const float* p1_wl = (const float*)d_in[8];
    const float* p1_bl = (const float*)d_in[9];
    const float* p1_wr = (const float*)d_in[10];
    const float* p2_wl = (const float*)d_in[11];
    const float* p2_bl = (const float*)d_in[12];
    const float* p2_wr = (const float*)d_in[13];
    const float* amp_w = (const float*)d_in[14];   // [3,64,64]
    const float* amp_b = (const float*)d_in[15];   // [3,64]
    const float* apm_w = (const float*)d_in[16];
    const float* apm_b = (const float*)d_in[17];
    const float* fc1_w = (const float*)d_in[18];
    const float* fc1_b = (const float*)d_in[19];
    const float* fc2_w = (const float*)d_in[20];
    const float* fc2_b = (const float*)d_in[21];
    const int* edge_mol  = (const int*)d_in[22];
    const int* edge_prot = (const int*)d_in[23];
    const int* batch_mol  = (const int*)d_in[24];
    const int* batch_prot = (const int*)d_in[25];
    float* out = (float*)d_out;

    const int N_MOL  = in_sizes[0] / 32;
    const int N_PROT = in_sizes[1] / 64;
    const int E_MOL  = in_sizes[22] / 2;
    const int E_PROT = in_sizes[23] / 2;

    // workspace layout (floats)
    float* w = (float*)d_ws;
    float* agg     = w;               w += (size_t)N_PROT * D;   // 524288
    float* cnt     = w;               w += N_PROT;               // 8192
    float* h_mol1  = w;               w += (size_t)N_MOL * D;
    float* h_mol2  = w;               w += (size_t)N_MOL * D;
    float* h_prot1 = w;               w += (size_t)N_PROT * D;
    float* h_prot2 = w;               w += (size_t)N_PROT * D;
    float* Qm      = w;               w += (size_t)N_MOL * D;
    float* Kp      = w;               w += (size_t)N_PROT * D;
    float* Vp      = w;               w += (size_t)N_PROT * D;
    float* Qp      = w;               w += (size_t)N_PROT * D;
    float* Km      = w;               w += (size_t)N_MOL * D;
    float* Vm      = w;               w += (size_t)N_MOL * D;
    float* h_mol_c = w;               w += (size_t)N_MOL * D;
    float* h_prot_c= w;               w += (size_t)N_PROT * D;
    float* zsum    = w;               w += NB * 128;
    float* zcnt    = w;               w += NB * 2;

    const size_t aggBytes = ((size_t)N_PROT * D + N_PROT) * sizeof(float);
    const int BLK = 256;
    dim3 blk(BLK);

    // ---- SAGE mol layer 1 (FIN=32) ----
    hipMemsetAsync(agg, 0, aggBytes, stream);
    {
        long total = (long)E_MOL * 32;
        int nb = (int)((total + BLK - 1) / BLK); if (nb > 4096) nb = 4096;
        k_agg<<<nb, blk, 0, stream>>>(x_mol, edge_mol, E_MOL, 5, agg, cnt);
        k_sage<32><<<(N_MOL + 3) / 4, blk, 0, stream>>>(x_mol, agg, cnt, N_MOL, m1_wl, m1_bl, m1_wr, h_mol1);
    }
    // ---- SAGE mol layer 2 (FIN=64) ----
    hipMemsetAsync(agg, 0, aggBytes, stream);
    {
        long total = (long)E_MOL * 64;
        int nb = (int)((total + BLK - 1) / BLK); if (nb > 4096) nb = 4096;
        k_agg<<<nb, blk, 0, stream>>>(h_mol1, edge_mol, E_MOL, 6, agg, cnt);
        k_sage<64><<<(N_MOL + 3) / 4, blk, 0, stream>>>(h_mol1, agg, cnt, N_MOL, m2_wl, m2_bl, m2_wr, h_mol2);
    }
    // ---- SAGE prot layer 1 (FIN=64) ----
    hipMemsetAsync(agg, 0, aggBytes, stream);
    {
        long total = (long)E_PROT * 64;
        int nb = (int)((total + BLK - 1) / BLK); if (nb > 8192) nb = 8192;
        k_agg<<<nb, blk, 0, stream>>>(x_prot, edge_prot, E_PROT, 6, agg, cnt);
        k_sage<64><<<(N_PROT + 3) / 4, blk, 0, stream>>>(x_prot, agg, cnt, N_PROT, p1_wl, p1_bl, p1_wr, h_prot1);
    }
    // ---- SAGE prot layer 2 (FIN=64) ----
    hipMemsetAsync(agg, 0, aggBytes, stream);
    {
        long total = (long)E_PROT * 64;
        int nb = (int)((total + BLK - 1) / BLK); if (nb > 8192) nb = 8192;
        k_agg<<<nb, blk, 0, stream>>>(h_prot1, edge_prot, E_PROT, 6, agg, cnt);
        k_sage<64><<<(N_PROT + 3) / 4, blk, 0, stream>>>(h_prot1, agg, cnt, N_PROT, p2_wl, p2_bl, p2_wr, h_prot2);
    }

    // ---- QKV projections ----
    k_linear<<<(N_MOL + 3) / 4,  blk, 0, stream>>>(h_mol2,  N_MOL,  amp_w + 0 * 4096, amp_b + 0,   Qm);
    k_linear<<<(N_PROT + 3) / 4, blk, 0, stream>>>(h_prot2, N_PROT, amp_w + 1 * 4096, amp_b + 64,  Kp);
    k_linear<<<(N_PROT + 3) / 4, blk, 0, stream>>>(h_prot2, N_PROT, amp_w + 2 * 4096, amp_b + 128, Vp);
    k_linear<<<(N_PROT + 3) / 4, blk, 0, stream>>>(h_prot2, N_PROT, apm_w + 0 * 4096, apm_b + 0,   Qp);
    k_linear<<<(N_MOL + 3) / 4,  blk, 0, stream>>>(h_mol2,  N_MOL,  apm_w + 1 * 4096, apm_b + 64,  Km);
    k_linear<<<(N_MOL + 3) / 4,  blk, 0, stream>>>(h_mol2,  N_MOL,  apm_w + 2 * 4096, apm_b + 128, Vm);

    // ---- cross attention (+residual) ----
    k_attn<<<N_MOL,  blk, 0, stream>>>(Qm, Kp, Vp, N_MOL,  N_PROT, h_mol2,  h_mol_c);
    k_attn<<<N_PROT, blk, 0, stream>>>(Qp, Km, Vm, N_PROT, N_MOL,  h_prot2, h_prot_c);

    // ---- pooling ----
    hipMemsetAsync(zsum, 0, (NB * 128 + NB * 2) * sizeof(float), stream);
    k_pool<<<(N_MOL * D + BLK - 1) / BLK,  blk, 0, stream>>>(h_mol_c,  batch_mol,  N_MOL,  0,  zsum, zcnt);
    k_pool<<<(N_PROT * D + BLK - 1) / BLK, blk, 0, stream>>>(h_prot_c, batch_prot, N_PROT, 64, zsum, zcnt);

    // ---- head ----
    k_head<<<1, blk, 0, stream>>>(zsum, zcnt, fc1_w, fc1_b, fc2_w, fc2_b, out);
}

// Round 2
// 668.889 us; speedup vs baseline: 3.3261x; 3.3261x over previous
//
#include <hip/hip_runtime.h>
#include <math.h>

#define D 64
#define NH 4
#define DH 16
#define NB 64

typedef __attribute__((ext_vector_type(8))) short bf16x8;
typedef __attribute__((ext_vector_type(4))) float f32x4;

__device__ __forceinline__ unsigned short f2bf(float f) {
    unsigned u = __float_as_uint(f);
    u += 0x7FFF + ((u >> 16) & 1);
    return (unsigned short)(u >> 16);
}

// ---------------------------------------------------------------------------
// Scatter-add aggregation for SAGE mean: agg[dst] += x[src], cnt[dst] += 1
// ---------------------------------------------------------------------------
__global__ void k_agg(const float* __restrict__ x, const int* __restrict__ edge,
                      int E, int logF, float* __restrict__ agg, float* __restrict__ cnt) {
    int F = 1 << logF;
    long total = (long)E << logF;
    long stride = (long)gridDim.x * blockDim.x;
    for (long i = (long)blockIdx.x * blockDim.x + threadIdx.x; i < total; i += stride) {
        int e = (int)(i >> logF);
        int f = (int)(i & (F - 1));
        int s = edge[e];
        int d = edge[E + e];
        atomicAdd(&agg[(long)d * F + f], x[(long)s * F + f]);
        if (f == 0) atomicAdd(&cnt[d], 1.0f);
    }
}

// ---------------------------------------------------------------------------
// SAGE linear: out = relu((agg/max(cnt,1)) @ wl + bl + x @ wr)
// ---------------------------------------------------------------------------
template<int FIN>
__global__ void k_sage(const float* __restrict__ x, const float* __restrict__ agg,
                       const float* __restrict__ cnt, int N,
                       const float* __restrict__ wl, const float* __restrict__ bl,
                       const float* __restrict__ wr, float* __restrict__ out) {
    __shared__ float swl[FIN * D];
    __shared__ float swr[FIN * D];
    for (int i = threadIdx.x; i < FIN * D; i += blockDim.x) { swl[i] = wl[i]; swr[i] = wr[i]; }
    __syncthreads();
    const int rpb = 4;
    int c = threadIdx.x & 63;
    for (int r = blockIdx.x * rpb + (threadIdx.x >> 6); r < N; r += gridDim.x * rpb) {
        float inv = 1.0f / fmaxf(cnt[r], 1.0f);
        float acc = bl[c];
        #pragma unroll 8
        for (int k = 0; k < FIN; ++k) {
            acc += agg[r * FIN + k] * inv * swl[k * D + c];
            acc += x[r * FIN + k] * swr[k * D + c];
        }
        out[r * D + c] = fmaxf(acc, 0.0f);
    }
}

// ---------------------------------------------------------------------------
// Linear projection -> bf16 output, optional scale folded in (for Q)
// ---------------------------------------------------------------------------
__global__ void k_linear_bf16(const float* __restrict__ x, int N,
                              const float* __restrict__ w, const float* __restrict__ b,
                              float scale, unsigned short* __restrict__ out) {
    __shared__ float sw[D * D];
    for (int i = threadIdx.x; i < D * D; i += blockDim.x) sw[i] = w[i];
    __syncthreads();
    int r = blockIdx.x * 4 + (threadIdx.x >> 6);
    int c = threadIdx.x & 63;
    if (r >= N) return;
    float acc = b[c];
    #pragma unroll 8
    for (int k = 0; k < D; ++k) acc += x[r * D + k] * sw[k * D + c];
    out[r * D + c] = f2bf(acc * scale);
}

// ---------------------------------------------------------------------------
// Transpose [N,64] bf16 -> [64,N] bf16 via LDS tiles (N multiple of 64)
// ---------------------------------------------------------------------------
__global__ void k_transpose64(const unsigned short* __restrict__ in,
                              unsigned short* __restrict__ out, int N) {
    __shared__ unsigned short tile[64][72];
    int t = threadIdx.x;
    int rbase = blockIdx.x * 64;
    {
        int r = t >> 2, c0 = (t & 3) * 16;
        const uint4* src = (const uint4*)(in + (size_t)(rbase + r) * 64 + c0);
        uint4 a = src[0], b = src[1];
        *(uint4*)(&tile[r][c0]) = a;
        *(uint4*)(&tile[r][c0 + 8]) = b;
    }
    __syncthreads();
    {
        int c = t >> 2, r0 = (t & 3) * 16;
        union { uint4 v[2]; unsigned short s[16]; } u;
        #pragma unroll
        for (int i = 0; i < 16; ++i) u.s[i] = tile[r0 + i][c];
        uint4* dst = (uint4*)(out + (size_t)c * N + rbase + r0);
        dst[0] = u.v[0];
        dst[1] = u.v[1];
    }
}

// ---------------------------------------------------------------------------
// Flash-style MFMA cross-attention. One wave per (16-query tile, head).
// Qb: [Nq,64] bf16, pre-scaled by 0.25*log2(e). Kb: [Nk,64] bf16.
// Vt: [64,Nk] bf16 (transposed). out = resid + softmax(QK^T)V   (fp32)
// A-frag: row=lane&15, k=(lane>>4)*8+j.  B-frag: col=lane&15, k=(lane>>4)*8+j.
// C/D:    col=lane&15, row=(lane>>4)*4+reg.
// ---------------------------------------------------------------------------
__global__ __launch_bounds__(256) void k_attn_mfma(
        const unsigned short* __restrict__ Qb,
        const unsigned short* __restrict__ Kb,
        const unsigned short* __restrict__ Vt,
        int Nq, int Nk,
        const float* __restrict__ resid, float* __restrict__ out) {
    __shared__ unsigned short P[4][16][40];  // per-wave P tile, padded rows (80B)
    const int w = threadIdx.x >> 6;
    const int lane = threadIdx.x & 63;
    const int job = blockIdx.x * 4 + w;      // (qtile, head)
    const int qt = job >> 2;
    const int h16 = (job & 3) * 16;
    const int g = lane >> 4;
    const int ln = lane & 15;

    bf16x8 qa = {0, 0, 0, 0, 0, 0, 0, 0};
    if (g < 2)
        qa = *(const bf16x8*)(Qb + ((size_t)(qt * 16 + ln) * 64 + h16 + g * 8));

    f32x4 o = {0.f, 0.f, 0.f, 0.f};
    float m[4], l[4];
    #pragma unroll
    for (int r = 0; r < 4; ++r) { m[r] = -1e30f; l[r] = 0.f; }

    for (int kb = 0; kb < Nk; kb += 32) {
        bf16x8 b0 = {0, 0, 0, 0, 0, 0, 0, 0};
        bf16x8 b1 = {0, 0, 0, 0, 0, 0, 0, 0};
        if (g < 2) {
            const unsigned short* kp = Kb + ((size_t)(kb + ln) * 64 + h16 + g * 8);
            b0 = *(const bf16x8*)kp;
            b1 = *(const bf16x8*)(kp + 16 * 64);
        }
        f32x4 z = {0.f, 0.f, 0.f, 0.f};
        f32x4 s0 = __builtin_amdgcn_mfma_f32_16x16x32_bf16(qa, b0, z, 0, 0, 0);
        f32x4 s1 = __builtin_amdgcn_mfma_f32_16x16x32_bf16(qa, b1, z, 0, 0, 0);
        #pragma unroll
        for (int r = 0; r < 4; ++r) {
            float a = fmaxf(s0[r], s1[r]);
            a = fmaxf(a, __shfl_xor(a, 1));
            a = fmaxf(a, __shfl_xor(a, 2));
            a = fmaxf(a, __shfl_xor(a, 4));
            a = fmaxf(a, __shfl_xor(a, 8));
            float nm = fmaxf(m[r], a);
            float sc = exp2f(m[r] - nm);
            float p0 = exp2f(s0[r] - nm);
            float p1 = exp2f(s1[r] - nm);
            float sum = p0 + p1;
            sum += __shfl_xor(sum, 1);
            sum += __shfl_xor(sum, 2);
            sum += __shfl_xor(sum, 4);
            sum += __shfl_xor(sum, 8);
            l[r] = l[r] * sc + sum;
            o[r] *= sc;
            m[r] = nm;
            P[w][g * 4 + r][ln] = f2bf(p0);
            P[w][g * 4 + r][16 + ln] = f2bf(p1);
        }
        bf16x8 pa = *(const bf16x8*)(&P[w][ln][g * 8]);
        bf16x8 vb = *(const bf16x8*)(Vt + ((size_t)(h16 + ln) * Nk + kb + g * 8));
        o = __builtin_amdgcn_mfma_f32_16x16x32_bf16(pa, vb, o, 0, 0, 0);
    }
    #pragma unroll
    for (int r = 0; r < 4; ++r) {
        int idx = (qt * 16 + g * 4 + r) * 64 + h16 + ln;
        out[idx] = resid[idx] + o[r] / l[r];
    }
}

// ---------------------------------------------------------------------------
// Segment-sum pooling
// ---------------------------------------------------------------------------
__global__ void k_pool(const float* __restrict__ h, const int* __restrict__ batch,
                       int N, int colOff, float* __restrict__ zsum, float* __restrict__ zcnt) {
    int idx = blockIdx.x * blockDim.x + threadIdx.x;
    if (idx >= N * D) return;
    int n = idx >> 6;
    int c = idx & 63;
    int b = batch[n];
    atomicAdd(&zsum[b * 128 + colOff + c], h[idx]);
    if (c == 0) atomicAdd(&zcnt[b * 2 + (colOff ? 1 : 0)], 1.0f);
}

// ---------------------------------------------------------------------------
// Head MLP
// ---------------------------------------------------------------------------
__global__ void k_head(const float* __restrict__ zsum, const float* __restrict__ zcnt,
                       const float* __restrict__ fc1w, const float* __restrict__ fc1b,
                       const float* __restrict__ fc2w, const float* __restrict__ fc2b,
                       float* __restrict__ out) {
    __shared__ float z[NB * 128];
    __shared__ float x1[NB * D];
    int t = threadIdx.x;
    for (int i = t; i < NB * 128; i += blockDim.x) {
        int b = i >> 7;
        int c = i & 127;
        float cn = zcnt[b * 2 + (c >> 6)];
        z[i] = zsum[i] / fmaxf(cn, 1.0f);
    }
    __syncthreads();
    for (int i = t; i < NB * D; i += blockDim.x) {
        int b = i >> 6;
        int c = i & 63;
        float acc = fc1b[c];
        #pragma unroll 8
        for (int k = 0; k < 128; ++k) acc += z[b * 128 + k] * fc1w[k * D + c];
        x1[i] = fmaxf(acc, 0.0f);
    }
    __syncthreads();
    if (t < NB) {
        float acc = fc2b[0];
        #pragma unroll 8
        for (int c = 0; c < D; ++c) acc += x1[t * D + c] * fc2w[c];
        out[t] = 1.0f / (1.0f + __expf(-acc));
    }
}

// ---------------------------------------------------------------------------
extern "C" void kernel_launch(void* const* d_in, const int* in_sizes, int n_in,
                              void* d_out, int out_size, void* d_ws, size_t ws_size,
                              hipStream_t stream) {
    const float* x_mol  = (const float*)d_in[0];
    const float* x_prot = (const float*)d_in[1];
    const float* m1_wl = (const float*)d_in[2];
    const float* m1_bl = (const float*)d_in[3];
    const float* m1_wr = (const float*)d_in[4];
    const float* m2_wl = (const float*)d_in[5];
    const float* m2_bl = (const float*)d_in[6];
    const float* m2_wr = (const float*)d_in[7];
    const float* p1_wl = (const float*)d_in[8];
    const float* p1_bl = (const float*)d_in[9];
    const float* p1_wr = (const float*)d_in[10];
    const float* p2_wl = (const float*)d_in[11];
    const float* p2_bl = (const float*)d_in[12];
    const float* p2_wr = (const float*)d_in[13];
    const float* amp_w = (const float*)d_in[14];
    const float* amp_b = (const float*)d_in[15];
    const float* apm_w = (const float*)d_in[16];
    const float* apm_b = (const float*)d_in[17];
    const float* fc1_w = (const float*)d_in[18];
    const float* fc1_b = (const float*)d_in[19];
    const float* fc2_w = (const float*)d_in[20];
    const float* fc2_b = (const float*)d_in[21];
    const int* edge_mol  = (const int*)d_in[22];
    const int* edge_prot = (const int*)d_in[23];
    const int* batch_mol  = (const int*)d_in[24];
    const int* batch_prot = (const int*)d_in[25];
    float* out = (float*)d_out;

    const int N_MOL  = in_sizes[0] / 32;
    const int N_PROT = in_sizes[1] / 64;
    const int E_MOL  = in_sizes[22] / 2;
    const int E_PROT = in_sizes[23] / 2;

    // ---- workspace bump allocator (256B aligned blocks) ----
    char* base = (char*)d_ws;
    size_t off = 0;
    auto alloc = [&](size_t bytes) -> void* {
        void* p = base + off;
        off = (off + bytes + 255) & ~(size_t)255;
        return p;
    };
    float* agg      = (float*)alloc(((size_t)N_PROT * D + N_PROT) * sizeof(float));
    float* cnt      = agg + (size_t)N_PROT * D;
    float* h_mol1   = (float*)alloc((size_t)N_MOL * D * sizeof(float));
    float* h_mol2   = (float*)alloc((size_t)N_MOL * D * sizeof(float));
    float* h_prot1  = (float*)alloc((size_t)N_PROT * D * sizeof(float));
    float* h_prot2  = (float*)alloc((size_t)N_PROT * D * sizeof(float));
    float* h_mol_c  = (float*)alloc((size_t)N_MOL * D * sizeof(float));
    float* h_prot_c = (float*)alloc((size_t)N_PROT * D * sizeof(float));
    float* zsum     = (float*)alloc((NB * 128 + NB * 2) * sizeof(float));
    float* zcnt     = zsum + NB * 128;
    unsigned short* Qm_b = (unsigned short*)alloc((size_t)N_MOL * D * 2);
    unsigned short* Km_b = (unsigned short*)alloc((size_t)N_MOL * D * 2);
    unsigned short* Vm_b = (unsigned short*)alloc((size_t)N_MOL * D * 2);
    unsigned short* Vm_t = (unsigned short*)alloc((size_t)N_MOL * D * 2);
    unsigned short* Qp_b = (unsigned short*)alloc((size_t)N_PROT * D * 2);
    unsigned short* Kp_b = (unsigned short*)alloc((size_t)N_PROT * D * 2);
    unsigned short* Vp_b = (unsigned short*)alloc((size_t)N_PROT * D * 2);
    unsigned short* Vp_t = (unsigned short*)alloc((size_t)N_PROT * D * 2);

    const size_t aggBytes = ((size_t)N_PROT * D + N_PROT) * sizeof(float);
    const int BLK = 256;
    dim3 blk(BLK);
    const float QS = 0.25f * 1.4426950408889634f;  // 1/sqrt(DH) * log2(e)

    // ---- SAGE mol layer 1 (FIN=32) ----
    hipMemsetAsync(agg, 0, aggBytes, stream);
    {
        long total = (long)E_MOL * 32;
        int nb = (int)((total + BLK - 1) / BLK); if (nb > 4096) nb = 4096;
        k_agg<<<nb, blk, 0, stream>>>(x_mol, edge_mol, E_MOL, 5, agg, cnt);
        k_sage<32><<<(N_MOL + 3) / 4, blk, 0, stream>>>(x_mol, agg, cnt, N_MOL, m1_wl, m1_bl, m1_wr, h_mol1);
    }
    // ---- SAGE mol layer 2 ----
    hipMemsetAsync(agg, 0, aggBytes, stream);
    {
        long total = (long)E_MOL * 64;
        int nb = (int)((total + BLK - 1) / BLK); if (nb > 4096) nb = 4096;
        k_agg<<<nb, blk, 0, stream>>>(h_mol1, edge_mol, E_MOL, 6, agg, cnt);
        k_sage<64><<<(N_MOL + 3) / 4, blk, 0, stream>>>(h_mol1, agg, cnt, N_MOL, m2_wl, m2_bl, m2_wr, h_mol2);
    }
    // ---- SAGE prot layer 1 ----
    hipMemsetAsync(agg, 0, aggBytes, stream);
    {
        long total = (long)E_PROT * 64;
        int nb = (int)((total + BLK - 1) / BLK); if (nb > 8192) nb = 8192;
        k_agg<<<nb, blk, 0, stream>>>(x_prot, edge_prot, E_PROT, 6, agg, cnt);
        k_sage<64><<<(N_PROT + 3) / 4, blk, 0, stream>>>(x_prot, agg, cnt, N_PROT, p1_wl, p1_bl, p1_wr, h_prot1);
    }
    // ---- SAGE prot layer 2 ----
    hipMemsetAsync(agg, 0, aggBytes, stream);
    {
        long total = (long)E_PROT * 64;
        int nb = (int)((total + BLK - 1) / BLK); if (nb > 8192) nb = 8192;
        k_agg<<<nb, blk, 0, stream>>>(h_prot1, edge_prot, E_PROT, 6, agg, cnt);
        k_sage<64><<<(N_PROT + 3) / 4, blk, 0, stream>>>(h_prot1, agg, cnt, N_PROT, p2_wl, p2_bl, p2_wr, h_prot2);
    }

    // ---- QKV projections (bf16 out; Q pre-scaled) ----
    k_linear_bf16<<<(N_MOL + 3) / 4,  blk, 0, stream>>>(h_mol2,  N_MOL,  amp_w + 0 * 4096, amp_b + 0,   QS,   Qm_b);
    k_linear_bf16<<<(N_PROT + 3) / 4, blk, 0, stream>>>(h_prot2, N_PROT, amp_w + 1 * 4096, amp_b + 64,  1.0f, Kp_b);
    k_linear_bf16<<<(N_PROT + 3) / 4, blk, 0, stream>>>(h_prot2, N_PROT, amp_w + 2 * 4096, amp_b + 128, 1.0f, Vp_b);
    k_linear_bf16<<<(N_PROT + 3) / 4, blk, 0, stream>>>(h_prot2, N_PROT, apm_w + 0 * 4096, apm_b + 0,   QS,   Qp_b);
    k_linear_bf16<<<(N_MOL + 3) / 4,  blk, 0, stream>>>(h_mol2,  N_MOL,  apm_w + 1 * 4096, apm_b + 64,  1.0f, Km_b);
    k_linear_bf16<<<(N_MOL + 3) / 4,  blk, 0, stream>>>(h_mol2,  N_MOL,  apm_w + 2 * 4096, apm_b + 128, 1.0f, Vm_b);

    // ---- V transposes ----
    k_transpose64<<<N_PROT / 64, blk, 0, stream>>>(Vp_b, Vp_t, N_PROT);
    k_transpose64<<<N_MOL / 64,  blk, 0, stream>>>(Vm_b, Vm_t, N_MOL);

    // ---- MFMA cross attention (+residual) ----
    k_attn_mfma<<<N_MOL / 16,  blk, 0, stream>>>(Qm_b, Kp_b, Vp_t, N_MOL,  N_PROT, h_mol2,  h_mol_c);
    k_attn_mfma<<<N_PROT / 16, blk, 0, stream>>>(Qp_b, Km_b, Vm_t, N_PROT, N_MOL,  h_prot2, h_prot_c);

    // ---- pooling ----
    hipMemsetAsync(zsum, 0, (NB * 128 + NB * 2) * sizeof(float), stream);
    k_pool<<<(N_MOL * D + BLK - 1) / BLK,  blk, 0, stream>>>(h_mol_c,  batch_mol,  N_MOL,  0,  zsum, zcnt);
    k_pool<<<(N_PROT * D + BLK - 1) / BLK, blk, 0, stream>>>(h_prot_c, batch_prot, N_PROT, 64, zsum, zcnt);

    // ---- head ----
    k_head<<<1, blk, 0, stream>>>(zsum, zcnt, fc1_w, fc1_b, fc2_w, fc2_b, out);
}

// Round 3
// 560.098 us; speedup vs baseline: 3.9721x; 1.1942x over previous
//
#include <hip/hip_runtime.h>
#include <math.h>

#define D 64
#define NB 64

typedef __attribute__((ext_vector_type(8))) short bf16x8;
typedef __attribute__((ext_vector_type(4))) float f32x4;

__device__ __forceinline__ unsigned short f2bf(float f) {
    unsigned u = __float_as_uint(f);
    u += 0x7FFF + ((u >> 16) & 1);
    return (unsigned short)(u >> 16);
}
__device__ __forceinline__ unsigned pk_bf16(float lo, float hi) {
    unsigned r;
    asm("v_cvt_pk_bf16_f32 %0, %1, %2" : "=v"(r) : "v"(lo), "v"(hi));
    return r;
}

// ---------------------------------------------------------------------------
// Scatter-add aggregation, float4 per thread: agg[dst] += x[src]; cnt[dst]++
// ---------------------------------------------------------------------------
__global__ void k_agg4(const float* __restrict__ x, const int* __restrict__ edge,
                       int E, int logF4, float* __restrict__ agg, float* __restrict__ cnt) {
    int F4 = 1 << logF4;          // number of float4 groups per row
    int F = F4 << 2;
    long total = (long)E << logF4;
    long stride = (long)gridDim.x * blockDim.x;
    for (long i = (long)blockIdx.x * blockDim.x + threadIdx.x; i < total; i += stride) {
        int e = (int)(i >> logF4);
        int f = (int)(i & (F4 - 1)) << 2;
        int s = edge[e];
        int d = edge[E + e];
        float4 v = *(const float4*)(x + (size_t)s * F + f);
        float* ap = agg + (size_t)d * F + f;
        atomicAdd(ap + 0, v.x);
        atomicAdd(ap + 1, v.y);
        atomicAdd(ap + 2, v.z);
        atomicAdd(ap + 3, v.w);
        if (cnt && f == 0) atomicAdd(&cnt[d], 1.0f);
    }
}

// ---------------------------------------------------------------------------
// SAGE linear: out = relu((agg/max(cnt,1)) @ wl + bl + x @ wr)
// ---------------------------------------------------------------------------
template<int FIN>
__global__ void k_sage(const float* __restrict__ x, const float* __restrict__ agg,
                       const float* __restrict__ cnt, int N,
                       const float* __restrict__ wl, const float* __restrict__ bl,
                       const float* __restrict__ wr, float* __restrict__ out) {
    __shared__ float swl[FIN * D];
    __shared__ float swr[FIN * D];
    for (int i = threadIdx.x; i < FIN * D; i += blockDim.x) { swl[i] = wl[i]; swr[i] = wr[i]; }
    __syncthreads();
    const int rpb = 4;
    int c = threadIdx.x & 63;
    for (int r = blockIdx.x * rpb + (threadIdx.x >> 6); r < N; r += gridDim.x * rpb) {
        float inv = 1.0f / fmaxf(cnt[r], 1.0f);
        float acc = bl[c];
        #pragma unroll 8
        for (int k = 0; k < FIN; ++k) {
            acc += agg[r * FIN + k] * inv * swl[k * D + c];
            acc += x[r * FIN + k] * swr[k * D + c];
        }
        out[r * D + c] = fmaxf(acc, 0.0f);
    }
}

// ---------------------------------------------------------------------------
// Fused QKV projection -> bf16 (Q pre-scaled). 16 rows per block.
// ---------------------------------------------------------------------------
__global__ __launch_bounds__(256) void k_qkv(
        const float* __restrict__ x, int N,
        const float* __restrict__ wq, const float* __restrict__ bq, float qs,
        unsigned short* __restrict__ oq,
        const float* __restrict__ wk, const float* __restrict__ bk,
        unsigned short* __restrict__ ok,
        const float* __restrict__ wv, const float* __restrict__ bv,
        unsigned short* __restrict__ ov) {
    __shared__ float sq[D * D], sk[D * D], sv[D * D], sx[16 * D];
    for (int i = threadIdx.x; i < D * D; i += 256) { sq[i] = wq[i]; sk[i] = wk[i]; sv[i] = wv[i]; }
    int rbase = blockIdx.x * 16;
    for (int i = threadIdx.x; i < 16 * D; i += 256) sx[i] = x[(size_t)rbase * D + i];
    __syncthreads();
    int c = threadIdx.x & 63;
    int r0 = (threadIdx.x >> 6) * 4;
    for (int rr = 0; rr < 4; ++rr) {
        int r = r0 + rr;
        float aq = bq[c], ak = bk[c], av = bv[c];
        #pragma unroll 8
        for (int k = 0; k < D; ++k) {
            float xv = sx[r * D + k];
            aq += xv * sq[k * D + c];
            ak += xv * sk[k * D + c];
            av += xv * sv[k * D + c];
        }
        size_t o = (size_t)(rbase + r) * D + c;
        oq[o] = f2bf(aq * qs);
        ok[o] = f2bf(ak);
        ov[o] = f2bf(av);
    }
}

// ---------------------------------------------------------------------------
// Transpose [N,64] bf16 -> [64,N] bf16 with within-32-chunk key permutation:
// dst position p holds key keymap(p) = (p&7)<4 ? 4*(p>>3)+(p&7)
//                                             : 16+4*(p>>3)+((p&7)-4)
// (i.e. V[key] written at p = inv: k<16 -> ((k>>2)<<3)|(k&3), else |4)
// This makes the attn PV B-fragment assemble from packed P words in-lane.
// ---------------------------------------------------------------------------
__global__ void k_transpose_perm(const unsigned short* __restrict__ in,
                                 unsigned short* __restrict__ out, int N) {
    __shared__ unsigned short tile[64][72];
    int t = threadIdx.x;
    int rbase = blockIdx.x * 64;
    {
        int r = t >> 2, c0 = (t & 3) * 16;
        const uint4* src = (const uint4*)(in + (size_t)(rbase + r) * 64 + c0);
        uint4 a = src[0], b = src[1];
        *(uint4*)(&tile[r][c0]) = a;
        *(uint4*)(&tile[r][c0 + 8]) = b;
    }
    __syncthreads();
    {
        int c = t >> 2, r0 = (t & 3) * 16;
        union { uint2 v2[4]; unsigned short s[16]; } u;
        #pragma unroll
        for (int i = 0; i < 16; ++i) u.s[i] = tile[r0 + i][c];
        int key0 = rbase + r0;
        int kc = key0 & ~31;
        int w = (key0 & 16) ? 4 : 0;
        unsigned short* op = out + (size_t)c * N;
        #pragma unroll
        for (int b = 0; b < 4; ++b)
            *(uint2*)(op + kc + b * 8 + w) = u.v2[b];
    }
}

// ---------------------------------------------------------------------------
// Split-K flash attention, swapped operands. One wave per (16-qtile, head).
// Computes S^T = mfma(K, Q^T): lane(g,ln) holds scores for query q=ln,
// keys kb+{g*4+r} (s0) and kb+16+{g*4+r} (s1). Softmax reduce is in-register
// + 2 shfl_xor. P packed to bf16 words feeds PV (O^T = V^T P^T) in-lane
// thanks to the permuted Vt. Partials (o unnormalized, m, l) to workspace.
// Q pre-scaled by (1/sqrt(DH))*log2(e); exp2 domain throughout.
// ---------------------------------------------------------------------------
__global__ __launch_bounds__(256) void k_attn_split(
        const unsigned short* __restrict__ Qb,
        const unsigned short* __restrict__ Kb,
        const unsigned short* __restrict__ Vt,
        int Nq, int Nk, int kchunk,
        float* __restrict__ po, float* __restrict__ pm, float* __restrict__ pl) {
    const int qt = blockIdx.x;
    const int split = blockIdx.y;
    const int h = threadIdx.x >> 6;
    const int lane = threadIdx.x & 63;
    const int g = lane >> 4;
    const int ln = lane & 15;
    const int h16 = h * 16;
    const int kstart = split * kchunk;

    bf16x8 qb = {0, 0, 0, 0, 0, 0, 0, 0};
    if (g < 2)
        qb = *(const bf16x8*)(Qb + ((size_t)(qt * 16 + ln) * D + h16 + g * 8));

    f32x4 o = {0.f, 0.f, 0.f, 0.f};
    float m = -1e30f, l = 0.f;
    const f32x4 z = {0.f, 0.f, 0.f, 0.f};

    for (int kb = kstart; kb < kstart + kchunk; kb += 32) {
        bf16x8 ka0 = {0, 0, 0, 0, 0, 0, 0, 0};
        bf16x8 ka1 = {0, 0, 0, 0, 0, 0, 0, 0};
        if (g < 2) {
            const unsigned short* kp = Kb + ((size_t)(kb + ln) * D + h16 + g * 8);
            ka0 = *(const bf16x8*)kp;
            ka1 = *(const bf16x8*)(kp + 16 * D);
        }
        f32x4 s0 = __builtin_amdgcn_mfma_f32_16x16x32_bf16(ka0, qb, z, 0, 0, 0);
        f32x4 s1 = __builtin_amdgcn_mfma_f32_16x16x32_bf16(ka1, qb, z, 0, 0, 0);

        float cm = fmaxf(fmaxf(fmaxf(s0[0], s0[1]), fmaxf(s0[2], s0[3])),
                         fmaxf(fmaxf(s1[0], s1[1]), fmaxf(s1[2], s1[3])));
        cm = fmaxf(cm, __shfl_xor(cm, 16));
        cm = fmaxf(cm, __shfl_xor(cm, 32));
        if (__any(cm > m + 8.f)) {          // deferred-max rescale (T13)
            float nm = fmaxf(m, cm);
            float sc = exp2f(m - nm);
            l *= sc;
            o[0] *= sc; o[1] *= sc; o[2] *= sc; o[3] *= sc;
            m = nm;
        }
        float p00 = exp2f(s0[0] - m), p01 = exp2f(s0[1] - m);
        float p02 = exp2f(s0[2] - m), p03 = exp2f(s0[3] - m);
        float p10 = exp2f(s1[0] - m), p11 = exp2f(s1[1] - m);
        float p12 = exp2f(s1[2] - m), p13 = exp2f(s1[3] - m);
        float ls = ((p00 + p01) + (p02 + p03)) + ((p10 + p11) + (p12 + p13));
        ls += __shfl_xor(ls, 16);
        ls += __shfl_xor(ls, 32);
        l += ls;

        union { unsigned u[4]; bf16x8 v; } pw;
        pw.u[0] = pk_bf16(p00, p01);   // keys 4g, 4g+1
        pw.u[1] = pk_bf16(p02, p03);   // keys 4g+2, 4g+3
        pw.u[2] = pk_bf16(p10, p11);   // keys 16+4g, 16+4g+1
        pw.u[3] = pk_bf16(p12, p13);   // keys 16+4g+2, 16+4g+3

        bf16x8 va = *(const bf16x8*)(Vt + ((size_t)(h16 + ln) * Nk + kb + g * 8));
        o = __builtin_amdgcn_mfma_f32_16x16x32_bf16(va, pw.v, o, 0, 0, 0);
    }

    size_t pbase = (size_t)split * Nq + qt * 16 + ln;
    float4 ov = {o[0], o[1], o[2], o[3]};
    *(float4*)(po + pbase * 64 + h16 + g * 4) = ov;
    if (lane < 16) {
        pm[pbase * 4 + h] = m;
        pl[pbase * 4 + h] = l;
    }
}

// ---------------------------------------------------------------------------
// Combine split-K partials: out = resid + (sum_s po_s*2^(m_s-M)) / (sum_s l_s*2^(m_s-M))
// ---------------------------------------------------------------------------
__global__ void k_combine(const float* __restrict__ po, const float* __restrict__ pm,
                          const float* __restrict__ pl, int nsplit, int Nq,
                          const float* __restrict__ resid, float* __restrict__ out) {
    int idx = blockIdx.x * blockDim.x + threadIdx.x;
    if (idx >= Nq * 64) return;
    int q = idx >> 6, d = idx & 63, h = d >> 4;
    float M = -1e30f;
    for (int s = 0; s < nsplit; ++s)
        M = fmaxf(M, pm[((size_t)s * Nq + q) * 4 + h]);
    float O = 0.f, L = 0.f;
    for (int s = 0; s < nsplit; ++s) {
        float wgt = exp2f(pm[((size_t)s * Nq + q) * 4 + h] - M);
        O += po[((size_t)s * Nq + q) * 64 + d] * wgt;
        L += pl[((size_t)s * Nq + q) * 4 + h] * wgt;
    }
    out[idx] = resid[idx] + O / L;
}

// ---------------------------------------------------------------------------
// Segment-sum pooling
// ---------------------------------------------------------------------------
__global__ void k_pool(const float* __restrict__ h, const int* __restrict__ batch,
                       int N, int colOff, float* __restrict__ zsum, float* __restrict__ zcnt) {
    int idx = blockIdx.x * blockDim.x + threadIdx.x;
    if (idx >= N * D) return;
    int n = idx >> 6;
    int c = idx & 63;
    int b = batch[n];
    atomicAdd(&zsum[b * 128 + colOff + c], h[idx]);
    if (c == 0) atomicAdd(&zcnt[b * 2 + (colOff ? 1 : 0)], 1.0f);
}

// ---------------------------------------------------------------------------
// Head MLP
// ---------------------------------------------------------------------------
__global__ void k_head(const float* __restrict__ zsum, const float* __restrict__ zcnt,
                       const float* __restrict__ fc1w, const float* __restrict__ fc1b,
                       const float* __restrict__ fc2w, const float* __restrict__ fc2b,
                       float* __restrict__ out) {
    __shared__ float z[NB * 128];
    __shared__ float x1[NB * D];
    int t = threadIdx.x;
    for (int i = t; i < NB * 128; i += blockDim.x) {
        int b = i >> 7;
        int c = i & 127;
        float cn = zcnt[b * 2 + (c >> 6)];
        z[i] = zsum[i] / fmaxf(cn, 1.0f);
    }
    __syncthreads();
    for (int i = t; i < NB * D; i += blockDim.x) {
        int b = i >> 6;
        int c = i & 63;
        float acc = fc1b[c];
        #pragma unroll 8
        for (int k = 0; k < 128; ++k) acc += z[b * 128 + k] * fc1w[k * D + c];
        x1[i] = fmaxf(acc, 0.0f);
    }
    __syncthreads();
    if (t < NB) {
        float acc = fc2b[0];
        #pragma unroll 8
        for (int c = 0; c < D; ++c) acc += x1[t * D + c] * fc2w[c];
        out[t] = 1.0f / (1.0f + __expf(-acc));
    }
}

// ---------------------------------------------------------------------------
extern "C" void kernel_launch(void* const* d_in, const int* in_sizes, int n_in,
                              void* d_out, int out_size, void* d_ws, size_t ws_size,
                              hipStream_t stream) {
    const float* x_mol  = (const float*)d_in[0];
    const float* x_prot = (const float*)d_in[1];
    const float* m1_wl = (const float*)d_in[2];
    const float* m1_bl = (const float*)d_in[3];
    const float* m1_wr = (const float*)d_in[4];
    const float* m2_wl = (const float*)d_in[5];
    const float* m2_bl = (const float*)d_in[6];
    const float* m2_wr = (const float*)d_in[7];
    const float* p1_wl = (const float*)d_in[8];
    const float* p1_bl = (const float*)d_in[9];
    const float* p1_wr = (const float*)d_in[10];
    const float* p2_wl = (const float*)d_in[11];
    const float* p2_bl = (const float*)d_in[12];
    const float* p2_wr = (const float*)d_in[13];
    const float* amp_w = (const float*)d_in[14];
    const float* amp_b = (const float*)d_in[15];
    const float* apm_w = (const float*)d_in[16];
    const float* apm_b = (const float*)d_in[17];
    const float* fc1_w = (const float*)d_in[18];
    const float* fc1_b = (const float*)d_in[19];
    const float* fc2_w = (const float*)d_in[20];
    const float* fc2_b = (const float*)d_in[21];
    const int* edge_mol  = (const int*)d_in[22];
    const int* edge_prot = (const int*)d_in[23];
    const int* batch_mol  = (const int*)d_in[24];
    const int* batch_prot = (const int*)d_in[25];
    float* out = (float*)d_out;

    const int N_MOL  = in_sizes[0] / 32;
    const int N_PROT = in_sizes[1] / 64;
    const int E_MOL  = in_sizes[22] / 2;
    const int E_PROT = in_sizes[23] / 2;

    // ---- workspace bump allocator ----
    char* base = (char*)d_ws;
    size_t off = 0;
    auto alloc = [&](size_t bytes) -> void* {
        void* p = base + off;
        off = (off + bytes + 255) & ~(size_t)255;
        return p;
    };
    float* agg      = (float*)alloc((size_t)N_PROT * D * sizeof(float));
    float* cnt_mol  = (float*)alloc((size_t)N_MOL * sizeof(float));
    float* cnt_prot = (float*)alloc((size_t)N_PROT * sizeof(float));
    float* h_mol1   = (float*)alloc((size_t)N_MOL * D * sizeof(float));
    float* h_mol2   = (float*)alloc((size_t)N_MOL * D * sizeof(float));
    float* h_prot1  = (float*)alloc((size_t)N_PROT * D * sizeof(float));
    float* h_prot2  = (float*)alloc((size_t)N_PROT * D * sizeof(float));
    float* h_mol_c  = (float*)alloc((size_t)N_MOL * D * sizeof(float));
    float* h_prot_c = (float*)alloc((size_t)N_PROT * D * sizeof(float));
    float* zsum     = (float*)alloc((NB * 128 + NB * 2) * sizeof(float));
    float* zcnt     = zsum + NB * 128;
    unsigned short* Qm_b = (unsigned short*)alloc((size_t)N_MOL * D * 2);
    unsigned short* Km_b = (unsigned short*)alloc((size_t)N_MOL * D * 2);
    unsigned short* Vm_b = (unsigned short*)alloc((size_t)N_MOL * D * 2);
    unsigned short* Vm_t = (unsigned short*)alloc((size_t)N_MOL * D * 2);
    unsigned short* Qp_b = (unsigned short*)alloc((size_t)N_PROT * D * 2);
    unsigned short* Kp_b = (unsigned short*)alloc((size_t)N_PROT * D * 2);
    unsigned short* Vp_b = (unsigned short*)alloc((size_t)N_PROT * D * 2);
    unsigned short* Vp_t = (unsigned short*)alloc((size_t)N_PROT * D * 2);

    // split-K factors (keys-per-split must be a multiple of 32)
    int nsm = 16; while (nsm > 1 && (N_PROT % (32 * nsm))) nsm >>= 1;  // mol queries prot keys
    int nsp = 4;  while (nsp > 1 && (N_MOL % (32 * nsp)))  nsp >>= 1;  // prot queries mol keys
    int maxPart = (nsm * N_MOL > nsp * N_PROT) ? nsm * N_MOL : nsp * N_PROT;
    float* po = (float*)alloc((size_t)maxPart * 64 * sizeof(float));
    float* pmb = (float*)alloc((size_t)maxPart * 4 * sizeof(float));
    float* plb = (float*)alloc((size_t)maxPart * 4 * sizeof(float));

    const int BLK = 256;
    dim3 blk(BLK);
    const float QS = 0.25f * 1.4426950408889634f;  // 1/sqrt(DH) * log2(e)

    hipMemsetAsync(cnt_mol, 0, (size_t)N_MOL * sizeof(float), stream);
    hipMemsetAsync(cnt_prot, 0, (size_t)N_PROT * sizeof(float), stream);

    // ---- SAGE mol layer 1 (FIN=32) ----
    hipMemsetAsync(agg, 0, (size_t)N_MOL * 32 * sizeof(float), stream);
    {
        long total = (long)E_MOL * 8;
        int nb = (int)((total + BLK - 1) / BLK); if (nb > 4096) nb = 4096;
        k_agg4<<<nb, blk, 0, stream>>>(x_mol, edge_mol, E_MOL, 3, agg, cnt_mol);
        k_sage<32><<<(N_MOL + 3) / 4, blk, 0, stream>>>(x_mol, agg, cnt_mol, N_MOL, m1_wl, m1_bl, m1_wr, h_mol1);
    }
    // ---- SAGE mol layer 2 (FIN=64), cnt reused ----
    hipMemsetAsync(agg, 0, (size_t)N_MOL * D * sizeof(float), stream);
    {
        long total = (long)E_MOL * 16;
        int nb = (int)((total + BLK - 1) / BLK); if (nb > 4096) nb = 4096;
        k_agg4<<<nb, blk, 0, stream>>>(h_mol1, edge_mol, E_MOL, 4, agg, nullptr);
        k_sage<64><<<(N_MOL + 3) / 4, blk, 0, stream>>>(h_mol1, agg, cnt_mol, N_MOL, m2_wl, m2_bl, m2_wr, h_mol2);
    }
    // ---- SAGE prot layer 1 ----
    hipMemsetAsync(agg, 0, (size_t)N_PROT * D * sizeof(float), stream);
    {
        long total = (long)E_PROT * 16;
        int nb = (int)((total + BLK - 1) / BLK); if (nb > 8192) nb = 8192;
        k_agg4<<<nb, blk, 0, stream>>>(x_prot, edge_prot, E_PROT, 4, agg, cnt_prot);
        k_sage<64><<<(N_PROT + 3) / 4, blk, 0, stream>>>(x_prot, agg, cnt_prot, N_PROT, p1_wl, p1_bl, p1_wr, h_prot1);
    }
    // ---- SAGE prot layer 2, cnt reused ----
    hipMemsetAsync(agg, 0, (size_t)N_PROT * D * sizeof(float), stream);
    {
        long total = (long)E_PROT * 16;
        int nb = (int)((total + BLK - 1) / BLK); if (nb > 8192) nb = 8192;
        k_agg4<<<nb, blk, 0, stream>>>(h_prot1, edge_prot, E_PROT, 4, agg, nullptr);
        k_sage<64><<<(N_PROT + 3) / 4, blk, 0, stream>>>(h_prot1, agg, cnt_prot, N_PROT, p2_wl, p2_bl, p2_wr, h_prot2);
    }

    // ---- fused QKV projections (bf16; Q pre-scaled into exp2 domain) ----
    k_qkv<<<N_MOL / 16, blk, 0, stream>>>(h_mol2, N_MOL,
        amp_w + 0 * 4096, amp_b + 0, QS, Qm_b,
        apm_w + 1 * 4096, apm_b + 64, Km_b,
        apm_w + 2 * 4096, apm_b + 128, Vm_b);
    k_qkv<<<N_PROT / 16, blk, 0, stream>>>(h_prot2, N_PROT,
        apm_w + 0 * 4096, apm_b + 0, QS, Qp_b,
        amp_w + 1 * 4096, amp_b + 64, Kp_b,
        amp_w + 2 * 4096, amp_b + 128, Vp_b);

    // ---- permuted V transposes ----
    k_transpose_perm<<<N_PROT / 64, blk, 0, stream>>>(Vp_b, Vp_t, N_PROT);
    k_transpose_perm<<<N_MOL / 64,  blk, 0, stream>>>(Vm_b, Vm_t, N_MOL);

    // ---- split-K flash attention + combine (+residual) ----
    k_attn_split<<<dim3(N_MOL / 16, nsm), blk, 0, stream>>>(
        Qm_b, Kp_b, Vp_t, N_MOL, N_PROT, N_PROT / nsm, po, pmb, plb);
    k_combine<<<(N_MOL * 64 + BLK - 1) / BLK, blk, 0, stream>>>(
        po, pmb, plb, nsm, N_MOL, h_mol2, h_mol_c);
    k_attn_split<<<dim3(N_PROT / 16, nsp), blk, 0, stream>>>(
        Qp_b, Km_b, Vm_t, N_PROT, N_MOL, N_MOL / nsp, po, pmb, plb);
    k_combine<<<(N_PROT * 64 + BLK - 1) / BLK, blk, 0, stream>>>(
        po, pmb, plb, nsp, N_PROT, h_prot2, h_prot_c);

    // ---- pooling ----
    hipMemsetAsync(zsum, 0, (NB * 128 + NB * 2) * sizeof(float), stream);
    k_pool<<<(N_MOL * D + BLK - 1) / BLK,  blk, 0, stream>>>(h_mol_c,  batch_mol,  N_MOL,  0,  zsum, zcnt);
    k_pool<<<(N_PROT * D + BLK - 1) / BLK, blk, 0, stream>>>(h_prot_c, batch_prot, N_PROT, 64, zsum, zcnt);

    // ---- head ----
    k_head<<<1, blk, 0, stream>>>(zsum, zcnt, fc1_w, fc1_b, fc2_w, fc2_b, out);
}

// Round 4
// 332.174 us; speedup vs baseline: 6.6976x; 1.6862x over previous
//
#include <hip/hip_runtime.h>
#include <math.h>

#define D 64
#define NB 64

typedef __attribute__((ext_vector_type(8))) short bf16x8;
typedef __attribute__((ext_vector_type(4))) float f32x4;

__device__ __forceinline__ unsigned short f2bf(float f) {
    unsigned u = __float_as_uint(f);
    u += 0x7FFF + ((u >> 16) & 1);
    return (unsigned short)(u >> 16);
}
__device__ __forceinline__ unsigned pk_bf16(float lo, float hi) {
    unsigned r;
    asm("v_cvt_pk_bf16_f32 %0, %1, %2" : "=v"(r) : "v"(lo), "v"(hi));
    return r;
}

// ---------------------------------------------------------------------------
// CSR build: histogram of dst degrees
// ---------------------------------------------------------------------------
__global__ void k_hist(const int* __restrict__ edge, int E, int* __restrict__ deg) {
    int i = blockIdx.x * blockDim.x + threadIdx.x;
    if (i < E) atomicAdd(&deg[edge[E + i]], 1);
}

// ---------------------------------------------------------------------------
// CSR build: exclusive prefix sum over deg[0..N) -> rowptr[0..N], cursor copy.
// Single block, 256 threads, chunked + Hillis-Steele on chunk totals.
// ---------------------------------------------------------------------------
__global__ void k_scan(const int* __restrict__ deg, int N,
                       int* __restrict__ rowptr, int* __restrict__ cursor) {
    __shared__ int chunk[256];
    int t = threadIdx.x;
    int C = (N + 255) / 256;
    int start = t * C;
    int sum = 0;
    for (int i = 0; i < C; ++i)
        if (start + i < N) sum += deg[start + i];
    chunk[t] = sum;
    __syncthreads();
    for (int ofs = 1; ofs < 256; ofs <<= 1) {
        int v = (t >= ofs) ? chunk[t - ofs] : 0;
        __syncthreads();
        chunk[t] += v;
        __syncthreads();
    }
    int base = (t == 0) ? 0 : chunk[t - 1];
    for (int i = 0; i < C && start + i < N; ++i) {
        rowptr[start + i] = base;
        cursor[start + i] = base;
        base += deg[start + i];
    }
    if (t == 255) rowptr[N] = base;
}

// ---------------------------------------------------------------------------
// CSR build: scatter src indices into buckets
// ---------------------------------------------------------------------------
__global__ void k_scatter(const int* __restrict__ edge, int E,
                          int* __restrict__ cursor, int* __restrict__ csr_src) {
    int i = blockIdx.x * blockDim.x + threadIdx.x;
    if (i >= E) return;
    int s = edge[i];
    int d = edge[E + i];
    int pos = atomicAdd(&cursor[d], 1);
    csr_src[pos] = s;
}

// ---------------------------------------------------------------------------
// CSR gather: agg[r] = sum_{e in row r} x[csr_src[e]]   (no atomics)
// F=64: one wave per row. F=32: two rows per wave.
// ---------------------------------------------------------------------------
template<int F>
__global__ void k_gather(const float* __restrict__ x, const int* __restrict__ rowptr,
                         const int* __restrict__ csr_src, int N, float* __restrict__ agg) {
    int gid = blockIdx.x * blockDim.x + threadIdx.x;
    int lane = threadIdx.x & 63;
    int r, f;
    if (F == 64) { r = gid >> 6; f = lane; }
    else         { r = ((gid >> 6) << 1) + (lane >> 5); f = lane & 31; }
    if (r >= N) return;
    int e0 = rowptr[r], e1 = rowptr[r + 1];
    float a0 = 0.f, a1 = 0.f;
    int e = e0;
    for (; e + 1 < e1; e += 2) {
        a0 += x[(size_t)csr_src[e] * F + f];
        a1 += x[(size_t)csr_src[e + 1] * F + f];
    }
    if (e < e1) a0 += x[(size_t)csr_src[e] * F + f];
    agg[(size_t)r * F + f] = a0 + a1;
}

// ---------------------------------------------------------------------------
// SAGE linear: out = relu((agg/deg) @ wl + bl + x @ wr); deg from rowptr
// ---------------------------------------------------------------------------
template<int FIN>
__global__ void k_sage(const float* __restrict__ x, const float* __restrict__ agg,
                       const int* __restrict__ rowptr, int N,
                       const float* __restrict__ wl, const float* __restrict__ bl,
                       const float* __restrict__ wr, float* __restrict__ out) {
    __shared__ float swl[FIN * D];
    __shared__ float swr[FIN * D];
    for (int i = threadIdx.x; i < FIN * D; i += blockDim.x) { swl[i] = wl[i]; swr[i] = wr[i]; }
    __syncthreads();
    const int rpb = 4;
    int c = threadIdx.x & 63;
    for (int r = blockIdx.x * rpb + (threadIdx.x >> 6); r < N; r += gridDim.x * rpb) {
        float inv = 1.0f / fmaxf((float)(rowptr[r + 1] - rowptr[r]), 1.0f);
        float acc = bl[c];
        #pragma unroll 8
        for (int k = 0; k < FIN; ++k) {
            acc += agg[r * FIN + k] * inv * swl[k * D + c];
            acc += x[r * FIN + k] * swr[k * D + c];
        }
        out[r * D + c] = fmaxf(acc, 0.0f);
    }
}

// ---------------------------------------------------------------------------
// Fused QKV projection -> bf16 (Q pre-scaled). 16 rows per block.
// ---------------------------------------------------------------------------
__global__ __launch_bounds__(256) void k_qkv(
        const float* __restrict__ x, int N,
        const float* __restrict__ wq, const float* __restrict__ bq, float qs,
        unsigned short* __restrict__ oq,
        const float* __restrict__ wk, const float* __restrict__ bk,
        unsigned short* __restrict__ ok,
        const float* __restrict__ wv, const float* __restrict__ bv,
        unsigned short* __restrict__ ov) {
    __shared__ float sq[D * D], sk[D * D], sv[D * D], sx[16 * D];
    for (int i = threadIdx.x; i < D * D; i += 256) { sq[i] = wq[i]; sk[i] = wk[i]; sv[i] = wv[i]; }
    int rbase = blockIdx.x * 16;
    for (int i = threadIdx.x; i < 16 * D; i += 256) sx[i] = x[(size_t)rbase * D + i];
    __syncthreads();
    int c = threadIdx.x & 63;
    int r0 = (threadIdx.x >> 6) * 4;
    for (int rr = 0; rr < 4; ++rr) {
        int r = r0 + rr;
        float aq = bq[c], ak = bk[c], av = bv[c];
        #pragma unroll 8
        for (int k = 0; k < D; ++k) {
            float xv = sx[r * D + k];
            aq += xv * sq[k * D + c];
            ak += xv * sk[k * D + c];
            av += xv * sv[k * D + c];
        }
        size_t o = (size_t)(rbase + r) * D + c;
        oq[o] = f2bf(aq * qs);
        ok[o] = f2bf(ak);
        ov[o] = f2bf(av);
    }
}

// ---------------------------------------------------------------------------
// Transpose [N,64] bf16 -> [64,N] bf16 with within-32-chunk key permutation
// (see attn kernel: makes PV B-fragment assemble in-lane from packed P words)
// ---------------------------------------------------------------------------
__global__ void k_transpose_perm(const unsigned short* __restrict__ in,
                                 unsigned short* __restrict__ out, int N) {
    __shared__ unsigned short tile[64][72];
    int t = threadIdx.x;
    int rbase = blockIdx.x * 64;
    {
        int r = t >> 2, c0 = (t & 3) * 16;
        const uint4* src = (const uint4*)(in + (size_t)(rbase + r) * 64 + c0);
        uint4 a = src[0], b = src[1];
        *(uint4*)(&tile[r][c0]) = a;
        *(uint4*)(&tile[r][c0 + 8]) = b;
    }
    __syncthreads();
    {
        int c = t >> 2, r0 = (t & 3) * 16;
        union { uint2 v2[4]; unsigned short s[16]; } u;
        #pragma unroll
        for (int i = 0; i < 16; ++i) u.s[i] = tile[r0 + i][c];
        int key0 = rbase + r0;
        int kc = key0 & ~31;
        int w = (key0 & 16) ? 4 : 0;
        unsigned short* op = out + (size_t)c * N;
        #pragma unroll
        for (int b = 0; b < 4; ++b)
            *(uint2*)(op + kc + b * 8 + w) = u.v2[b];
    }
}

// ---------------------------------------------------------------------------
// Split-K flash attention, swapped operands (S^T = mfma(K, Q)).
// One wave per (16-qtile, head, split). Partials (o, m, l) to workspace.
// ---------------------------------------------------------------------------
__global__ __launch_bounds__(256) void k_attn_split(
        const unsigned short* __restrict__ Qb,
        const unsigned short* __restrict__ Kb,
        const unsigned short* __restrict__ Vt,
        int Nq, int Nk, int kchunk,
        float* __restrict__ po, float* __restrict__ pm, float* __restrict__ pl) {
    const int qt = blockIdx.x;
    const int split = blockIdx.y;
    const int h = threadIdx.x >> 6;
    const int lane = threadIdx.x & 63;
    const int g = lane >> 4;
    const int ln = lane & 15;
    const int h16 = h * 16;
    const int kstart = split * kchunk;

    bf16x8 qb = {0, 0, 0, 0, 0, 0, 0, 0};
    if (g < 2)
        qb = *(const bf16x8*)(Qb + ((size_t)(qt * 16 + ln) * D + h16 + g * 8));

    f32x4 o = {0.f, 0.f, 0.f, 0.f};
    float m = -1e30f, l = 0.f;
    const f32x4 z = {0.f, 0.f, 0.f, 0.f};

    for (int kb = kstart; kb < kstart + kchunk; kb += 32) {
        bf16x8 ka0 = {0, 0, 0, 0, 0, 0, 0, 0};
        bf16x8 ka1 = {0, 0, 0, 0, 0, 0, 0, 0};
        if (g < 2) {
            const unsigned short* kp = Kb + ((size_t)(kb + ln) * D + h16 + g * 8);
            ka0 = *(const bf16x8*)kp;
            ka1 = *(const bf16x8*)(kp + 16 * D);
        }
        f32x4 s0 = __builtin_amdgcn_mfma_f32_16x16x32_bf16(ka0, qb, z, 0, 0, 0);
        f32x4 s1 = __builtin_amdgcn_mfma_f32_16x16x32_bf16(ka1, qb, z, 0, 0, 0);

        float cm = fmaxf(fmaxf(fmaxf(s0[0], s0[1]), fmaxf(s0[2], s0[3])),
                         fmaxf(fmaxf(s1[0], s1[1]), fmaxf(s1[2], s1[3])));
        cm = fmaxf(cm, __shfl_xor(cm, 16));
        cm = fmaxf(cm, __shfl_xor(cm, 32));
        if (__any(cm > m + 8.f)) {          // deferred-max rescale (T13)
            float nm = fmaxf(m, cm);
            float sc = exp2f(m - nm);
            l *= sc;
            o[0] *= sc; o[1] *= sc; o[2] *= sc; o[3] *= sc;
            m = nm;
        }
        float p00 = exp2f(s0[0] - m), p01 = exp2f(s0[1] - m);
        float p02 = exp2f(s0[2] - m), p03 = exp2f(s0[3] - m);
        float p10 = exp2f(s1[0] - m), p11 = exp2f(s1[1] - m);
        float p12 = exp2f(s1[2] - m), p13 = exp2f(s1[3] - m);
        float ls = ((p00 + p01) + (p02 + p03)) + ((p10 + p11) + (p12 + p13));
        ls += __shfl_xor(ls, 16);
        ls += __shfl_xor(ls, 32);
        l += ls;

        union { unsigned u[4]; bf16x8 v; } pw;
        pw.u[0] = pk_bf16(p00, p01);
        pw.u[1] = pk_bf16(p02, p03);
        pw.u[2] = pk_bf16(p10, p11);
        pw.u[3] = pk_bf16(p12, p13);

        bf16x8 va = *(const bf16x8*)(Vt + ((size_t)(h16 + ln) * Nk + kb + g * 8));
        o = __builtin_amdgcn_mfma_f32_16x16x32_bf16(va, pw.v, o, 0, 0, 0);
    }

    size_t pbase = (size_t)split * Nq + qt * 16 + ln;
    float4 ov = {o[0], o[1], o[2], o[3]};
    *(float4*)(po + pbase * 64 + h16 + g * 4) = ov;
    if (lane < 16) {
        pm[pbase * 4 + h] = m;
        pl[pbase * 4 + h] = l;
    }
}

// ---------------------------------------------------------------------------
// Combine split-K partials
// ---------------------------------------------------------------------------
__global__ void k_combine(const float* __restrict__ po, const float* __restrict__ pm,
                          const float* __restrict__ pl, int nsplit, int Nq,
                          const float* __restrict__ resid, float* __restrict__ out) {
    int idx = blockIdx.x * blockDim.x + threadIdx.x;
    if (idx >= Nq * 64) return;
    int q = idx >> 6, d = idx & 63, h = d >> 4;
    float M = -1e30f;
    for (int s = 0; s < nsplit; ++s)
        M = fmaxf(M, pm[((size_t)s * Nq + q) * 4 + h]);
    float O = 0.f, L = 0.f;
    for (int s = 0; s < nsplit; ++s) {
        float wgt = exp2f(pm[((size_t)s * Nq + q) * 4 + h] - M);
        O += po[((size_t)s * Nq + q) * 64 + d] * wgt;
        L += pl[((size_t)s * Nq + q) * 4 + h] * wgt;
    }
    out[idx] = resid[idx] + O / L;
}

// ---------------------------------------------------------------------------
// Segment pooling over sorted batch ids: register-run accumulation,
// atomics only at run boundaries.
// ---------------------------------------------------------------------------
__global__ void k_pool(const float* __restrict__ h, const int* __restrict__ batch,
                       int N, int colOff, float* __restrict__ zsum, float* __restrict__ zcnt) {
    int w = threadIdx.x >> 6, c = threadIdx.x & 63;
    int n0 = blockIdx.x * 64 + w * 16;
    if (n0 >= N) return;
    int n1 = n0 + 16 < N ? n0 + 16 : N;
    int curb = batch[n0];
    float acc = 0.f;
    int cnt = 0;
    for (int n = n0; n < n1; ++n) {
        int b = batch[n];
        if (b != curb) {
            atomicAdd(&zsum[curb * 128 + colOff + c], acc);
            if (c == 0) atomicAdd(&zcnt[curb * 2 + (colOff ? 1 : 0)], (float)cnt);
            acc = 0.f; cnt = 0; curb = b;
        }
        acc += h[(size_t)n * 64 + c];
        ++cnt;
    }
    atomicAdd(&zsum[curb * 128 + colOff + c], acc);
    if (c == 0) atomicAdd(&zcnt[curb * 2 + (colOff ? 1 : 0)], (float)cnt);
}

// ---------------------------------------------------------------------------
// Head MLP
// ---------------------------------------------------------------------------
__global__ void k_head(const float* __restrict__ zsum, const float* __restrict__ zcnt,
                       const float* __restrict__ fc1w, const float* __restrict__ fc1b,
                       const float* __restrict__ fc2w, const float* __restrict__ fc2b,
                       float* __restrict__ out) {
    __shared__ float z[NB * 128];
    __shared__ float x1[NB * D];
    int t = threadIdx.x;
    for (int i = t; i < NB * 128; i += blockDim.x) {
        int b = i >> 7;
        int c = i & 127;
        float cn = zcnt[b * 2 + (c >> 6)];
        z[i] = zsum[i] / fmaxf(cn, 1.0f);
    }
    __syncthreads();
    for (int i = t; i < NB * D; i += blockDim.x) {
        int b = i >> 6;
        int c = i & 63;
        float acc = fc1b[c];
        #pragma unroll 8
        for (int k = 0; k < 128; ++k) acc += z[b * 128 + k] * fc1w[k * D + c];
        x1[i] = fmaxf(acc, 0.0f);
    }
    __syncthreads();
    if (t < NB) {
        float acc = fc2b[0];
        #pragma unroll 8
        for (int c = 0; c < D; ++c) acc += x1[t * D + c] * fc2w[c];
        out[t] = 1.0f / (1.0f + __expf(-acc));
    }
}

// ---------------------------------------------------------------------------
extern "C" void kernel_launch(void* const* d_in, const int* in_sizes, int n_in,
                              void* d_out, int out_size, void* d_ws, size_t ws_size,
                              hipStream_t stream) {
    const float* x_mol  = (const float*)d_in[0];
    const float* x_prot = (const float*)d_in[1];
    const float* m1_wl = (const float*)d_in[2];
    const float* m1_bl = (const float*)d_in[3];
    const float* m1_wr = (const float*)d_in[4];
    const float* m2_wl = (const float*)d_in[5];
    const float* m2_bl = (const float*)d_in[6];
    const float* m2_wr = (const float*)d_in[7];
    const float* p1_wl = (const float*)d_in[8];
    const float* p1_bl = (const float*)d_in[9];
    const float* p1_wr = (const float*)d_in[10];
    const float* p2_wl = (const float*)d_in[11];
    const float* p2_bl = (const float*)d_in[12];
    const float* p2_wr = (const float*)d_in[13];
    const float* amp_w = (const float*)d_in[14];
    const float* amp_b = (const float*)d_in[15];
    const float* apm_w = (const float*)d_in[16];
    const float* apm_b = (const float*)d_in[17];
    const float* fc1_w = (const float*)d_in[18];
    const float* fc1_b = (const float*)d_in[19];
    const float* fc2_w = (const float*)d_in[20];
    const float* fc2_b = (const float*)d_in[21];
    const int* edge_mol  = (const int*)d_in[22];
    const int* edge_prot = (const int*)d_in[23];
    const int* batch_mol  = (const int*)d_in[24];
    const int* batch_prot = (const int*)d_in[25];
    float* out = (float*)d_out;

    const int N_MOL  = in_sizes[0] / 32;
    const int N_PROT = in_sizes[1] / 64;
    const int E_MOL  = in_sizes[22] / 2;
    const int E_PROT = in_sizes[23] / 2;

    // ---- workspace bump allocator ----
    char* base = (char*)d_ws;
    size_t off = 0;
    auto alloc = [&](size_t bytes) -> void* {
        void* p = base + off;
        off = (off + bytes + 255) & ~(size_t)255;
        return p;
    };
    float* agg      = (float*)alloc((size_t)N_PROT * D * sizeof(float));
    float* h_mol1   = (float*)alloc((size_t)N_MOL * D * sizeof(float));
    float* h_mol2   = (float*)alloc((size_t)N_MOL * D * sizeof(float));
    float* h_prot1  = (float*)alloc((size_t)N_PROT * D * sizeof(float));
    float* h_prot2  = (float*)alloc((size_t)N_PROT * D * sizeof(float));
    float* h_mol_c  = (float*)alloc((size_t)N_MOL * D * sizeof(float));
    float* h_prot_c = (float*)alloc((size_t)N_PROT * D * sizeof(float));
    float* zsum     = (float*)alloc((NB * 128 + NB * 2) * sizeof(float));
    float* zcnt     = zsum + NB * 128;
    unsigned short* Qm_b = (unsigned short*)alloc((size_t)N_MOL * D * 2);
    unsigned short* Km_b = (unsigned short*)alloc((size_t)N_MOL * D * 2);
    unsigned short* Vm_b = (unsigned short*)alloc((size_t)N_MOL * D * 2);
    unsigned short* Vm_t = (unsigned short*)alloc((size_t)N_MOL * D * 2);
    unsigned short* Qp_b = (unsigned short*)alloc((size_t)N_PROT * D * 2);
    unsigned short* Kp_b = (unsigned short*)alloc((size_t)N_PROT * D * 2);
    unsigned short* Vp_b = (unsigned short*)alloc((size_t)N_PROT * D * 2);
    unsigned short* Vp_t = (unsigned short*)alloc((size_t)N_PROT * D * 2);
    // CSR
    int* deg_m    = (int*)alloc((size_t)N_MOL * sizeof(int));
    int* rp_m     = (int*)alloc(((size_t)N_MOL + 1) * sizeof(int));
    int* cur_m    = (int*)alloc((size_t)N_MOL * sizeof(int));
    int* csr_m    = (int*)alloc((size_t)E_MOL * sizeof(int));
    int* deg_p    = (int*)alloc((size_t)N_PROT * sizeof(int));
    int* rp_p     = (int*)alloc(((size_t)N_PROT + 1) * sizeof(int));
    int* cur_p    = (int*)alloc((size_t)N_PROT * sizeof(int));
    int* csr_p    = (int*)alloc((size_t)E_PROT * sizeof(int));

    // split-K factors
    int nsm = 16; while (nsm > 1 && (N_PROT % (32 * nsm))) nsm >>= 1;
    int nsp = 4;  while (nsp > 1 && (N_MOL % (32 * nsp)))  nsp >>= 1;
    int maxPart = (nsm * N_MOL > nsp * N_PROT) ? nsm * N_MOL : nsp * N_PROT;
    float* po  = (float*)alloc((size_t)maxPart * 64 * sizeof(float));
    float* pmb = (float*)alloc((size_t)maxPart * 4 * sizeof(float));
    float* plb = (float*)alloc((size_t)maxPart * 4 * sizeof(float));

    const int BLK = 256;
    dim3 blk(BLK);
    const float QS = 0.25f * 1.4426950408889634f;  // 1/sqrt(DH) * log2(e)

    // ---- CSR build (once per graph type, reused by both SAGE layers) ----
    hipMemsetAsync(deg_m, 0, (size_t)N_MOL * sizeof(int), stream);
    hipMemsetAsync(deg_p, 0, (size_t)N_PROT * sizeof(int), stream);
    k_hist<<<(E_MOL + BLK - 1) / BLK, blk, 0, stream>>>(edge_mol, E_MOL, deg_m);
    k_hist<<<(E_PROT + BLK - 1) / BLK, blk, 0, stream>>>(edge_prot, E_PROT, deg_p);
    k_scan<<<1, blk, 0, stream>>>(deg_m, N_MOL, rp_m, cur_m);
    k_scan<<<1, blk, 0, stream>>>(deg_p, N_PROT, rp_p, cur_p);
    k_scatter<<<(E_MOL + BLK - 1) / BLK, blk, 0, stream>>>(edge_mol, E_MOL, cur_m, csr_m);
    k_scatter<<<(E_PROT + BLK - 1) / BLK, blk, 0, stream>>>(edge_prot, E_PROT, cur_p, csr_p);

    // ---- SAGE mol layer 1 (FIN=32) ----
    k_gather<32><<<(N_MOL / 2 + 3) / 4, blk, 0, stream>>>(x_mol, rp_m, csr_m, N_MOL, agg);
    k_sage<32><<<(N_MOL + 3) / 4, blk, 0, stream>>>(x_mol, agg, rp_m, N_MOL, m1_wl, m1_bl, m1_wr, h_mol1);
    // ---- SAGE mol layer 2 ----
    k_gather<64><<<(N_MOL + 3) / 4, blk, 0, stream>>>(h_mol1, rp_m, csr_m, N_MOL, agg);
    k_sage<64><<<(N_MOL + 3) / 4, blk, 0, stream>>>(h_mol1, agg, rp_m, N_MOL, m2_wl, m2_bl, m2_wr, h_mol2);
    // ---- SAGE prot layer 1 ----
    k_gather<64><<<(N_PROT + 3) / 4, blk, 0, stream>>>(x_prot, rp_p, csr_p, N_PROT, agg);
    k_sage<64><<<(N_PROT + 3) / 4, blk, 0, stream>>>(x_prot, agg, rp_p, N_PROT, p1_wl, p1_bl, p1_wr, h_prot1);
    // ---- SAGE prot layer 2 ----
    k_gather<64><<<(N_PROT + 3) / 4, blk, 0, stream>>>(h_prot1, rp_p, csr_p, N_PROT, agg);
    k_sage<64><<<(N_PROT + 3) / 4, blk, 0, stream>>>(h_prot1, agg, rp_p, N_PROT, p2_wl, p2_bl, p2_wr, h_prot2);

    // ---- fused QKV projections ----
    k_qkv<<<N_MOL / 16, blk, 0, stream>>>(h_mol2, N_MOL,
        amp_w + 0 * 4096, amp_b + 0, QS, Qm_b,
        apm_w + 1 * 4096, apm_b + 64, Km_b,
        apm_w + 2 * 4096, apm_b + 128, Vm_b);
    k_qkv<<<N_PROT / 16, blk, 0, stream>>>(h_prot2, N_PROT,
        apm_w + 0 * 4096, apm_b + 0, QS, Qp_b,
        amp_w + 1 * 4096, amp_b + 64, Kp_b,
        amp_w + 2 * 4096, amp_b + 128, Vp_b);

    // ---- permuted V transposes ----
    k_transpose_perm<<<N_PROT / 64, blk, 0, stream>>>(Vp_b, Vp_t, N_PROT);
    k_transpose_perm<<<N_MOL / 64,  blk, 0, stream>>>(Vm_b, Vm_t, N_MOL);

    // ---- split-K flash attention + combine (+residual) ----
    k_attn_split<<<dim3(N_MOL / 16, nsm), blk, 0, stream>>>(
        Qm_b, Kp_b, Vp_t, N_MOL, N_PROT, N_PROT / nsm, po, pmb, plb);
    k_combine<<<(N_MOL * 64 + BLK - 1) / BLK, blk, 0, stream>>>(
        po, pmb, plb, nsm, N_MOL, h_mol2, h_mol_c);
    k_attn_split<<<dim3(N_PROT / 16, nsp), blk, 0, stream>>>(
        Qp_b, Km_b, Vm_t, N_PROT, N_MOL, N_MOL / nsp, po, pmb, plb);
    k_combine<<<(N_PROT * 64 + BLK - 1) / BLK, blk, 0, stream>>>(
        po, pmb, plb, nsp, N_PROT, h_prot2, h_prot_c);

    // ---- pooling ----
    hipMemsetAsync(zsum, 0, (NB * 128 + NB * 2) * sizeof(float), stream);
    k_pool<<<(N_MOL + 63) / 64,  blk, 0, stream>>>(h_mol_c,  batch_mol,  N_MOL,  0,  zsum, zcnt);
    k_pool<<<(N_PROT + 63) / 64, blk, 0, stream>>>(h_prot_c, batch_prot, N_PROT, 64, zsum, zcnt);

    // ---- head ----
    k_head<<<1, blk, 0, stream>>>(zsum, zcnt, fc1_w, fc1_b, fc2_w, fc2_b, out);
}

// Round 5
// 266.393 us; speedup vs baseline: 8.3514x; 1.2469x over previous
//
#include <hip/hip_runtime.h>
#include <math.h>

#define D 64
#define NB 64

typedef __attribute__((ext_vector_type(8))) short bf16x8;
typedef __attribute__((ext_vector_type(4))) float f32x4;

__device__ __forceinline__ unsigned short f2bf(float f) {
    unsigned u = __float_as_uint(f);
    u += 0x7FFF + ((u >> 16) & 1);
    return (unsigned short)(u >> 16);
}
__device__ __forceinline__ unsigned pk_bf16(float lo, float hi) {
    unsigned r;
    asm("v_cvt_pk_bf16_f32 %0, %1, %2" : "=v"(r) : "v"(lo), "v"(hi));
    return r;
}

// ---------------------------------------------------------------------------
// CSR build (both graphs in one launch): histogram of dst degrees
// ---------------------------------------------------------------------------
__global__ void k_hist2(const int* __restrict__ em, int Em,
                        const int* __restrict__ ep, int Ep,
                        int* __restrict__ degm, int* __restrict__ degp) {
    int i = blockIdx.x * blockDim.x + threadIdx.x;
    if (i < Em) atomicAdd(&degm[em[Em + i]], 1);
    int j = i - Em;
    if (j >= 0 && j < Ep) atomicAdd(&degp[ep[Ep + j]], 1);
}

// ---------------------------------------------------------------------------
// CSR build: exclusive prefix sum (block 0 = mol, block 1 = prot).
// deg staged via LDS for coalesced global reads.
// ---------------------------------------------------------------------------
__global__ __launch_bounds__(256) void k_scan2(
        const int* __restrict__ degm, int Nm, int* __restrict__ rpm, int* __restrict__ curm,
        const int* __restrict__ degp, int Np, int* __restrict__ rpp, int* __restrict__ curp) {
    __shared__ int sdeg[8192];
    __shared__ int chunk[256];
    const int* deg = blockIdx.x ? degp : degm;
    int N = blockIdx.x ? Np : Nm;
    int* rowptr = blockIdx.x ? rpp : rpm;
    int* cursor = blockIdx.x ? curp : curm;
    int t = threadIdx.x;
    for (int i = t; i < N; i += 256) sdeg[i] = deg[i];
    __syncthreads();
    int C = (N + 255) / 256;
    int start = t * C;
    int sum = 0;
    for (int i = 0; i < C; ++i)
        if (start + i < N) sum += sdeg[start + i];
    chunk[t] = sum;
    __syncthreads();
    for (int ofs = 1; ofs < 256; ofs <<= 1) {
        int v = (t >= ofs) ? chunk[t - ofs] : 0;
        __syncthreads();
        chunk[t] += v;
        __syncthreads();
    }
    int base = (t == 0) ? 0 : chunk[t - 1];
    for (int i = 0; i < C && start + i < N; ++i) {
        rowptr[start + i] = base;
        cursor[start + i] = base;
        base += sdeg[start + i];
    }
    if (t == 255) rowptr[N] = base;
}

// ---------------------------------------------------------------------------
// CSR build: scatter src indices (both graphs in one launch)
// ---------------------------------------------------------------------------
__global__ void k_scatter2(const int* __restrict__ em, int Em, int* __restrict__ curm,
                           int* __restrict__ csrm,
                           const int* __restrict__ ep, int Ep, int* __restrict__ curp,
                           int* __restrict__ csrp) {
    int i = blockIdx.x * blockDim.x + threadIdx.x;
    if (i < Em) {
        int s = em[i], d = em[Em + i];
        csrm[atomicAdd(&curm[d], 1)] = s;
    }
    int j = i - Em;
    if (j >= 0 && j < Ep) {
        int s = ep[j], d = ep[Ep + j];
        csrp[atomicAdd(&curp[d], 1)] = s;
    }
}

// ---------------------------------------------------------------------------
// Fused gather + SAGE linear. One wave per row: gather mean of neighbor rows
// into LDS, then out[r] = relu(mean @ wl + bl + x[r] @ wr).
// ---------------------------------------------------------------------------
template<int FIN>
__global__ __launch_bounds__(256) void k_gsage(
        const float* __restrict__ x, const int* __restrict__ rowptr,
        const int* __restrict__ csr_src, int N,
        const float* __restrict__ wl, const float* __restrict__ bl,
        const float* __restrict__ wr, float* __restrict__ out) {
    __shared__ float swl[FIN * D];
    __shared__ float swr[FIN * D];
    __shared__ float sagg[4][FIN];
    __shared__ float sx[4][FIN];
    for (int i = threadIdx.x; i < FIN * D; i += 256) { swl[i] = wl[i]; swr[i] = wr[i]; }
    int w = threadIdx.x >> 6;
    int lane = threadIdx.x & 63;
    int r = blockIdx.x * 4 + w;
    if (r < N) {
        int e0 = rowptr[r], e1 = rowptr[r + 1];
        float inv = 1.0f / fmaxf((float)(e1 - e0), 1.0f);
        if (FIN == 64) {
            float a0 = 0.f, a1 = 0.f;
            int e = e0;
            for (; e + 1 < e1; e += 2) {
                a0 += x[(size_t)csr_src[e] * FIN + lane];
                a1 += x[(size_t)csr_src[e + 1] * FIN + lane];
            }
            if (e < e1) a0 += x[(size_t)csr_src[e] * FIN + lane];
            sagg[w][lane] = (a0 + a1) * inv;
            sx[w][lane] = x[(size_t)r * FIN + lane];
        } else {  // FIN == 32: two half-waves split the edge list
            int f = lane & 31, half = lane >> 5;
            float a = 0.f;
            for (int e = e0 + half; e < e1; e += 2)
                a += x[(size_t)csr_src[e] * FIN + f];
            a += __shfl_xor(a, 32);
            if (half == 0) {
                sagg[w][f] = a * inv;
                sx[w][f] = x[(size_t)r * FIN + f];
            }
        }
    }
    __syncthreads();
    if (r >= N) return;
    int c = lane;
    float acc = bl[c];
    #pragma unroll 8
    for (int k = 0; k < FIN; ++k) {
        acc += sagg[w][k] * swl[k * D + c];
        acc += sx[w][k] * swr[k * D + c];
    }
    out[(size_t)r * D + c] = fmaxf(acc, 0.0f);
}

// ---------------------------------------------------------------------------
// Fused QKV projection -> bf16 (Q pre-scaled). 16 rows per block.
// ---------------------------------------------------------------------------
__global__ __launch_bounds__(256) void k_qkv(
        const float* __restrict__ x, int N,
        const float* __restrict__ wq, const float* __restrict__ bq, float qs,
        unsigned short* __restrict__ oq,
        const float* __restrict__ wk, const float* __restrict__ bk,
        unsigned short* __restrict__ ok,
        const float* __restrict__ wv, const float* __restrict__ bv,
        unsigned short* __restrict__ ov) {
    __shared__ float sq[D * D], sk[D * D], sv[D * D], sx[16 * D];
    for (int i = threadIdx.x; i < D * D; i += 256) { sq[i] = wq[i]; sk[i] = wk[i]; sv[i] = wv[i]; }
    int rbase = blockIdx.x * 16;
    for (int i = threadIdx.x; i < 16 * D; i += 256) sx[i] = x[(size_t)rbase * D + i];
    __syncthreads();
    int c = threadIdx.x & 63;
    int r0 = (threadIdx.x >> 6) * 4;
    for (int rr = 0; rr < 4; ++rr) {
        int r = r0 + rr;
        float aq = bq[c], ak = bk[c], av = bv[c];
        #pragma unroll 8
        for (int k = 0; k < D; ++k) {
            float xv = sx[r * D + k];
            aq += xv * sq[k * D + c];
            ak += xv * sk[k * D + c];
            av += xv * sv[k * D + c];
        }
        size_t o = (size_t)(rbase + r) * D + c;
        oq[o] = f2bf(aq * qs);
        ok[o] = f2bf(ak);
        ov[o] = f2bf(av);
    }
}

// ---------------------------------------------------------------------------
// Transpose [N,64] bf16 -> [64,N] bf16 with within-32-chunk key permutation
// (makes attn PV B-fragment assemble in-lane from packed P words)
// ---------------------------------------------------------------------------
__global__ void k_transpose_perm(const unsigned short* __restrict__ in,
                                 unsigned short* __restrict__ out, int N) {
    __shared__ unsigned short tile[64][72];
    int t = threadIdx.x;
    int rbase = blockIdx.x * 64;
    {
        int r = t >> 2, c0 = (t & 3) * 16;
        const uint4* src = (const uint4*)(in + (size_t)(rbase + r) * 64 + c0);
        uint4 a = src[0], b = src[1];
        *(uint4*)(&tile[r][c0]) = a;
        *(uint4*)(&tile[r][c0 + 8]) = b;
    }
    __syncthreads();
    {
        int c = t >> 2, r0 = (t & 3) * 16;
        union { uint2 v2[4]; unsigned short s[16]; } u;
        #pragma unroll
        for (int i = 0; i < 16; ++i) u.s[i] = tile[r0 + i][c];
        int key0 = rbase + r0;
        int kc = key0 & ~31;
        int w = (key0 & 16) ? 4 : 0;
        unsigned short* op = out + (size_t)c * N;
        #pragma unroll
        for (int b = 0; b < 4; ++b)
            *(uint2*)(op + kc + b * 8 + w) = u.v2[b];
    }
}

// ---------------------------------------------------------------------------
// Split-K flash attention, swapped operands (S^T = mfma(K, Q)).
// One wave per (16-qtile, head, split). Partials (o, m, l) to workspace.
// ---------------------------------------------------------------------------
__global__ __launch_bounds__(256) void k_attn_split(
        const unsigned short* __restrict__ Qb,
        const unsigned short* __restrict__ Kb,
        const unsigned short* __restrict__ Vt,
        int Nq, int Nk, int kchunk,
        float* __restrict__ po, float* __restrict__ pm, float* __restrict__ pl) {
    const int qt = blockIdx.x;
    const int split = blockIdx.y;
    const int h = threadIdx.x >> 6;
    const int lane = threadIdx.x & 63;
    const int g = lane >> 4;
    const int ln = lane & 15;
    const int h16 = h * 16;
    const int kstart = split * kchunk;

    bf16x8 qb = {0, 0, 0, 0, 0, 0, 0, 0};
    if (g < 2)
        qb = *(const bf16x8*)(Qb + ((size_t)(qt * 16 + ln) * D + h16 + g * 8));

    f32x4 o = {0.f, 0.f, 0.f, 0.f};
    float m = -1e30f, l = 0.f;
    const f32x4 z = {0.f, 0.f, 0.f, 0.f};

    for (int kb = kstart; kb < kstart + kchunk; kb += 32) {
        bf16x8 ka0 = {0, 0, 0, 0, 0, 0, 0, 0};
        bf16x8 ka1 = {0, 0, 0, 0, 0, 0, 0, 0};
        if (g < 2) {
            const unsigned short* kp = Kb + ((size_t)(kb + ln) * D + h16 + g * 8);
            ka0 = *(const bf16x8*)kp;
            ka1 = *(const bf16x8*)(kp + 16 * D);
        }
        f32x4 s0 = __builtin_amdgcn_mfma_f32_16x16x32_bf16(ka0, qb, z, 0, 0, 0);
        f32x4 s1 = __builtin_amdgcn_mfma_f32_16x16x32_bf16(ka1, qb, z, 0, 0, 0);

        float cm = fmaxf(fmaxf(fmaxf(s0[0], s0[1]), fmaxf(s0[2], s0[3])),
                         fmaxf(fmaxf(s1[0], s1[1]), fmaxf(s1[2], s1[3])));
        cm = fmaxf(cm, __shfl_xor(cm, 16));
        cm = fmaxf(cm, __shfl_xor(cm, 32));
        if (__any(cm > m + 8.f)) {          // deferred-max rescale (T13)
            float nm = fmaxf(m, cm);
            float sc = exp2f(m - nm);
            l *= sc;
            o[0] *= sc; o[1] *= sc; o[2] *= sc; o[3] *= sc;
            m = nm;
        }
        float p00 = exp2f(s0[0] - m), p01 = exp2f(s0[1] - m);
        float p02 = exp2f(s0[2] - m), p03 = exp2f(s0[3] - m);
        float p10 = exp2f(s1[0] - m), p11 = exp2f(s1[1] - m);
        float p12 = exp2f(s1[2] - m), p13 = exp2f(s1[3] - m);
        float ls = ((p00 + p01) + (p02 + p03)) + ((p10 + p11) + (p12 + p13));
        ls += __shfl_xor(ls, 16);
        ls += __shfl_xor(ls, 32);
        l += ls;

        union { unsigned u[4]; bf16x8 v; } pw;
        pw.u[0] = pk_bf16(p00, p01);
        pw.u[1] = pk_bf16(p02, p03);
        pw.u[2] = pk_bf16(p10, p11);
        pw.u[3] = pk_bf16(p12, p13);

        bf16x8 va = *(const bf16x8*)(Vt + ((size_t)(h16 + ln) * Nk + kb + g * 8));
        o = __builtin_amdgcn_mfma_f32_16x16x32_bf16(va, pw.v, o, 0, 0, 0);
    }

    size_t pbase = (size_t)split * Nq + qt * 16 + ln;
    float4 ov = {o[0], o[1], o[2], o[3]};
    *(float4*)(po + pbase * 64 + h16 + g * 4) = ov;
    if (lane < 16) {
        pm[pbase * 4 + h] = m;
        pl[pbase * 4 + h] = l;
    }
}

// ---------------------------------------------------------------------------
// Fused combine + residual + segment pooling (straight to zsum via atomics)
// ---------------------------------------------------------------------------
__global__ void k_combine_pool(const float* __restrict__ po, const float* __restrict__ pm,
                               const float* __restrict__ pl, int nsplit, int Nq,
                               const float* __restrict__ resid,
                               const int* __restrict__ batch, int colOff,
                               float* __restrict__ zsum, float* __restrict__ zcnt) {
    int idx = blockIdx.x * blockDim.x + threadIdx.x;
    if (idx >= Nq * 64) return;
    int q = idx >> 6, d = idx & 63, h = d >> 4;
    float M = -1e30f;
    for (int s = 0; s < nsplit; ++s)
        M = fmaxf(M, pm[((size_t)s * Nq + q) * 4 + h]);
    float O = 0.f, L = 0.f;
    for (int s = 0; s < nsplit; ++s) {
        float wgt = exp2f(pm[((size_t)s * Nq + q) * 4 + h] - M);
        O += po[((size_t)s * Nq + q) * 64 + d] * wgt;
        L += pl[((size_t)s * Nq + q) * 4 + h] * wgt;
    }
    float val = resid[idx] + O / L;
    int b = batch[q];
    atomicAdd(&zsum[b * 128 + colOff + d], val);
    if (d == 0) atomicAdd(&zcnt[b * 2 + (colOff ? 1 : 0)], 1.0f);
}

// ---------------------------------------------------------------------------
// Head MLP: one wave per batch element; fc1 lane-per-col, fc2 via butterfly.
// ---------------------------------------------------------------------------
__global__ __launch_bounds__(256) void k_head2(
        const float* __restrict__ zsum, const float* __restrict__ zcnt,
        const float* __restrict__ fc1w, const float* __restrict__ fc1b,
        const float* __restrict__ fc2w, const float* __restrict__ fc2b,
        float* __restrict__ out) {
    int b = blockIdx.x * 4 + (threadIdx.x >> 6);
    int c = threadIdx.x & 63;
    float inv0 = 1.0f / fmaxf(zcnt[b * 2 + 0], 1.0f);
    float inv1 = 1.0f / fmaxf(zcnt[b * 2 + 1], 1.0f);
    float acc = fc1b[c];
    #pragma unroll 8
    for (int k = 0; k < 128; ++k) {
        float zv = zsum[b * 128 + k] * (k < 64 ? inv0 : inv1);
        acc += zv * fc1w[k * 64 + c];
    }
    float v = fmaxf(acc, 0.0f) * fc2w[c];
    #pragma unroll
    for (int off = 32; off > 0; off >>= 1) v += __shfl_xor(v, off);
    if (c == 0) out[b] = 1.0f / (1.0f + __expf(-(v + fc2b[0])));
}

// ---------------------------------------------------------------------------
extern "C" void kernel_launch(void* const* d_in, const int* in_sizes, int n_in,
                              void* d_out, int out_size, void* d_ws, size_t ws_size,
                              hipStream_t stream) {
    const float* x_mol  = (const float*)d_in[0];
    const float* x_prot = (const float*)d_in[1];
    const float* m1_wl = (const float*)d_in[2];
    const float* m1_bl = (const float*)d_in[3];
    const float* m1_wr = (const float*)d_in[4];
    const float* m2_wl = (const float*)d_in[5];
    const float* m2_bl = (const float*)d_in[6];
    const float* m2_wr = (const float*)d_in[7];
    const float* p1_wl = (const float*)d_in[8];
    const float* p1_bl = (const float*)d_in[9];
    const float* p1_wr = (const float*)d_in[10];
    const float* p2_wl = (const float*)d_in[11];
    const float* p2_bl = (const float*)d_in[12];
    const float* p2_wr = (const float*)d_in[13];
    const float* amp_w = (const float*)d_in[14];
    const float* amp_b = (const float*)d_in[15];
    const float* apm_w = (const float*)d_in[16];
    const float* apm_b = (const float*)d_in[17];
    const float* fc1_w = (const float*)d_in[18];
    const float* fc1_b = (const float*)d_in[19];
    const float* fc2_w = (const float*)d_in[20];
    const float* fc2_b = (const float*)d_in[21];
    const int* edge_mol  = (const int*)d_in[22];
    const int* edge_prot = (const int*)d_in[23];
    const int* batch_mol  = (const int*)d_in[24];
    const int* batch_prot = (const int*)d_in[25];
    float* out = (float*)d_out;

    const int N_MOL  = in_sizes[0] / 32;
    const int N_PROT = in_sizes[1] / 64;
    const int E_MOL  = in_sizes[22] / 2;
    const int E_PROT = in_sizes[23] / 2;

    // ---- workspace bump allocator ----
    char* base = (char*)d_ws;
    size_t off = 0;
    auto alloc = [&](size_t bytes) -> void* {
        void* p = base + off;
        off = (off + bytes + 255) & ~(size_t)255;
        return p;
    };
    float* h_mol1   = (float*)alloc((size_t)N_MOL * D * sizeof(float));
    float* h_mol2   = (float*)alloc((size_t)N_MOL * D * sizeof(float));
    float* h_prot1  = (float*)alloc((size_t)N_PROT * D * sizeof(float));
    float* h_prot2  = (float*)alloc((size_t)N_PROT * D * sizeof(float));
    float* zsum     = (float*)alloc((NB * 128 + NB * 2) * sizeof(float));
    float* zcnt     = zsum + NB * 128;
    unsigned short* Qm_b = (unsigned short*)alloc((size_t)N_MOL * D * 2);
    unsigned short* Km_b = (unsigned short*)alloc((size_t)N_MOL * D * 2);
    unsigned short* Vm_b = (unsigned short*)alloc((size_t)N_MOL * D * 2);
    unsigned short* Vm_t = (unsigned short*)alloc((size_t)N_MOL * D * 2);
    unsigned short* Qp_b = (unsigned short*)alloc((size_t)N_PROT * D * 2);
    unsigned short* Kp_b = (unsigned short*)alloc((size_t)N_PROT * D * 2);
    unsigned short* Vp_b = (unsigned short*)alloc((size_t)N_PROT * D * 2);
    unsigned short* Vp_t = (unsigned short*)alloc((size_t)N_PROT * D * 2);
    // CSR (deg_m/deg_p contiguous for single memset)
    int* deg      = (int*)alloc(((size_t)N_MOL + N_PROT) * sizeof(int));
    int* deg_m    = deg;
    int* deg_p    = deg + N_MOL;
    int* rp_m     = (int*)alloc(((size_t)N_MOL + 1) * sizeof(int));
    int* cur_m    = (int*)alloc((size_t)N_MOL * sizeof(int));
    int* csr_m    = (int*)alloc((size_t)E_MOL * sizeof(int));
    int* rp_p     = (int*)alloc(((size_t)N_PROT + 1) * sizeof(int));
    int* cur_p    = (int*)alloc((size_t)N_PROT * sizeof(int));
    int* csr_p    = (int*)alloc((size_t)E_PROT * sizeof(int));

    // split-K factors
    int nsm = 16; while (nsm > 1 && (N_PROT % (32 * nsm))) nsm >>= 1;
    int nsp = 4;  while (nsp > 1 && (N_MOL % (32 * nsp)))  nsp >>= 1;
    int maxPart = (nsm * N_MOL > nsp * N_PROT) ? nsm * N_MOL : nsp * N_PROT;
    float* po  = (float*)alloc((size_t)maxPart * 64 * sizeof(float));
    float* pmb = (float*)alloc((size_t)maxPart * 4 * sizeof(float));
    float* plb = (float*)alloc((size_t)maxPart * 4 * sizeof(float));

    const int BLK = 256;
    dim3 blk(BLK);
    const float QS = 0.25f * 1.4426950408889634f;  // 1/sqrt(DH) * log2(e)

    // ---- CSR build (both graphs; reused by both SAGE layers) ----
    hipMemsetAsync(deg, 0, ((size_t)N_MOL + N_PROT) * sizeof(int), stream);
    hipMemsetAsync(zsum, 0, (NB * 128 + NB * 2) * sizeof(float), stream);
    int Etot = E_MOL + E_PROT;
    k_hist2<<<(Etot + BLK - 1) / BLK, blk, 0, stream>>>(edge_mol, E_MOL, edge_prot, E_PROT, deg_m, deg_p);
    k_scan2<<<2, blk, 0, stream>>>(deg_m, N_MOL, rp_m, cur_m, deg_p, N_PROT, rp_p, cur_p);
    k_scatter2<<<(Etot + BLK - 1) / BLK, blk, 0, stream>>>(edge_mol, E_MOL, cur_m, csr_m,
                                                           edge_prot, E_PROT, cur_p, csr_p);

    // ---- SAGE layers (fused gather + linear) ----
    k_gsage<32><<<N_MOL / 4,  blk, 0, stream>>>(x_mol,   rp_m, csr_m, N_MOL,  m1_wl, m1_bl, m1_wr, h_mol1);
    k_gsage<64><<<N_MOL / 4,  blk, 0, stream>>>(h_mol1,  rp_m, csr_m, N_MOL,  m2_wl, m2_bl, m2_wr, h_mol2);
    k_gsage<64><<<N_PROT / 4, blk, 0, stream>>>(x_prot,  rp_p, csr_p, N_PROT, p1_wl, p1_bl, p1_wr, h_prot1);
    k_gsage<64><<<N_PROT / 4, blk, 0, stream>>>(h_prot1, rp_p, csr_p, N_PROT, p2_wl, p2_bl, p2_wr, h_prot2);

    // ---- fused QKV projections ----
    k_qkv<<<N_MOL / 16, blk, 0, stream>>>(h_mol2, N_MOL,
        amp_w + 0 * 4096, amp_b + 0, QS, Qm_b,
        apm_w + 1 * 4096, apm_b + 64, Km_b,
        apm_w + 2 * 4096, apm_b + 128, Vm_b);
    k_qkv<<<N_PROT / 16, blk, 0, stream>>>(h_prot2, N_PROT,
        apm_w + 0 * 4096, apm_b + 0, QS, Qp_b,
        amp_w + 1 * 4096, amp_b + 64, Kp_b,
        amp_w + 2 * 4096, amp_b + 128, Vp_b);

    // ---- permuted V transposes ----
    k_transpose_perm<<<N_PROT / 64, blk, 0, stream>>>(Vp_b, Vp_t, N_PROT);
    k_transpose_perm<<<N_MOL / 64,  blk, 0, stream>>>(Vm_b, Vm_t, N_MOL);

    // ---- split-K flash attention + fused combine/residual/pool ----
    k_attn_split<<<dim3(N_MOL / 16, nsm), blk, 0, stream>>>(
        Qm_b, Kp_b, Vp_t, N_MOL, N_PROT, N_PROT / nsm, po, pmb, plb);
    k_combine_pool<<<(N_MOL * 64 + BLK - 1) / BLK, blk, 0, stream>>>(
        po, pmb, plb, nsm, N_MOL, h_mol2, batch_mol, 0, zsum, zcnt);
    k_attn_split<<<dim3(N_PROT / 16, nsp), blk, 0, stream>>>(
        Qp_b, Km_b, Vm_t, N_PROT, N_MOL, N_MOL / nsp, po, pmb, plb);
    k_combine_pool<<<(N_PROT * 64 + BLK - 1) / BLK, blk, 0, stream>>>(
        po, pmb, plb, nsp, N_PROT, h_prot2, batch_prot, 64, zsum, zcnt);

    // ---- head ----
    k_head2<<<16, blk, 0, stream>>>(zsum, zcnt, fc1_w, fc1_b, fc2_w, fc2_b, out);
}

// Round 8
// 225.182 us; speedup vs baseline: 9.8798x; 1.1830x over previous
//
#include <hip/hip_runtime.h>
#include <math.h>

#define D 64
#define NB 64

typedef __attribute__((ext_vector_type(8))) short bf16x8;
typedef __attribute__((ext_vector_type(4))) float f32x4;
typedef __attribute__((ext_vector_type(16))) float f32x16;

__device__ __forceinline__ unsigned short f2bf(float f) {
    unsigned u = __float_as_uint(f);
    u += 0x7FFF + ((u >> 16) & 1);
    return (unsigned short)(u >> 16);
}
__device__ __forceinline__ unsigned pk_bf16(float lo, float hi) {
    unsigned r;
    asm("v_cvt_pk_bf16_f32 %0, %1, %2" : "=v"(r) : "v"(lo), "v"(hi));
    return r;
}

// ---------------------------------------------------------------------------
// CSR build: histogram of dst degrees (both graphs, one launch)
// ---------------------------------------------------------------------------
__global__ void k_hist2(const int* __restrict__ em, int Em,
                        const int* __restrict__ ep, int Ep,
                        int* __restrict__ degm, int* __restrict__ degp) {
    int i = blockIdx.x * blockDim.x + threadIdx.x;
    if (i < Em) atomicAdd(&degm[em[Em + i]], 1);
    int j = i - Em;
    if (j >= 0 && j < Ep) atomicAdd(&degp[ep[Ep + j]], 1);
}

// ---------------------------------------------------------------------------
// CSR build: exclusive prefix sum (block 0 = mol, block 1 = prot)
// ---------------------------------------------------------------------------
__global__ __launch_bounds__(256) void k_scan2(
        const int* __restrict__ degm, int Nm, int* __restrict__ rpm, int* __restrict__ curm,
        const int* __restrict__ degp, int Np, int* __restrict__ rpp, int* __restrict__ curp) {
    __shared__ int sdeg[8192];
    __shared__ int chunk[256];
    const int* deg = blockIdx.x ? degp : degm;
    int N = blockIdx.x ? Np : Nm;
    int* rowptr = blockIdx.x ? rpp : rpm;
    int* cursor = blockIdx.x ? curp : curm;
    int t = threadIdx.x;
    for (int i = t; i < N; i += 256) sdeg[i] = deg[i];
    __syncthreads();
    int C = (N + 255) / 256;
    int start = t * C;
    int sum = 0;
    for (int i = 0; i < C; ++i)
        if (start + i < N) sum += sdeg[start + i];
    chunk[t] = sum;
    __syncthreads();
    for (int ofs = 1; ofs < 256; ofs <<= 1) {
        int v = (t >= ofs) ? chunk[t - ofs] : 0;
        __syncthreads();
        chunk[t] += v;
        __syncthreads();
    }
    int base = (t == 0) ? 0 : chunk[t - 1];
    for (int i = 0; i < C && start + i < N; ++i) {
        rowptr[start + i] = base;
        cursor[start + i] = base;
        base += sdeg[start + i];
    }
    if (t == 255) rowptr[N] = base;
}

// ---------------------------------------------------------------------------
// CSR build: scatter src indices (both graphs, one launch)
// ---------------------------------------------------------------------------
__global__ void k_scatter2(const int* __restrict__ em, int Em, int* __restrict__ curm,
                           int* __restrict__ csrm,
                           const int* __restrict__ ep, int Ep, int* __restrict__ curp,
                           int* __restrict__ csrp) {
    int i = blockIdx.x * blockDim.x + threadIdx.x;
    if (i < Em) {
        int s = em[i], d = em[Em + i];
        csrm[atomicAdd(&curm[d], 1)] = s;
    }
    int j = i - Em;
    if (j >= 0 && j < Ep) {
        int s = ep[j], d = ep[Ep + j];
        csrp[atomicAdd(&curp[d], 1)] = s;
    }
}

// ---------------------------------------------------------------------------
// Fused gather + SAGE linear body (one wave per row)
// ---------------------------------------------------------------------------
template<int FIN>
__device__ __forceinline__ void gsage_body(
        const float* __restrict__ x, const int* __restrict__ rowptr,
        const int* __restrict__ csr, int N,
        const float* __restrict__ wl, const float* __restrict__ bl,
        const float* __restrict__ wr, float* __restrict__ out,
        int blk, float* __restrict__ swl, float* __restrict__ swr,
        float* __restrict__ sagg, float* __restrict__ sx) {
    for (int i = threadIdx.x; i < FIN * D; i += 256) { swl[i] = wl[i]; swr[i] = wr[i]; }
    int w = threadIdx.x >> 6;
    int lane = threadIdx.x & 63;
    int r = blk * 4 + w;
    if (r < N) {
        int e0 = rowptr[r], e1 = rowptr[r + 1];
        float inv = 1.0f / fmaxf((float)(e1 - e0), 1.0f);
        if (FIN == 64) {
            float a0 = 0.f, a1 = 0.f;
            int e = e0;
            for (; e + 1 < e1; e += 2) {
                a0 += x[(size_t)csr[e] * FIN + lane];
                a1 += x[(size_t)csr[e + 1] * FIN + lane];
            }
            if (e < e1) a0 += x[(size_t)csr[e] * FIN + lane];
            sagg[w * 64 + lane] = (a0 + a1) * inv;
            sx[w * 64 + lane] = x[(size_t)r * FIN + lane];
        } else {
            int f = lane & 31, half = lane >> 5;
            float a = 0.f;
            for (int e = e0 + half; e < e1; e += 2)
                a += x[(size_t)csr[e] * FIN + f];
            a += __shfl_xor(a, 32);
            if (half == 0) {
                sagg[w * 64 + f] = a * inv;
                sx[w * 64 + f] = x[(size_t)r * FIN + f];
            }
        }
    }
    __syncthreads();
    if (r >= N) return;
    int c = lane;
    float acc = bl[c];
    #pragma unroll 8
    for (int k = 0; k < FIN; ++k) {
        acc += sagg[w * 64 + k] * swl[k * D + c];
        acc += sx[w * 64 + k] * swr[k * D + c];
    }
    out[(size_t)r * D + c] = fmaxf(acc, 0.0f);
}

template<int FA, int FB>
__global__ __launch_bounds__(256) void k_gsage2(
        const float* __restrict__ xA, const int* __restrict__ rpA,
        const int* __restrict__ csrA, int NA,
        const float* __restrict__ wlA, const float* __restrict__ blA,
        const float* __restrict__ wrA, float* __restrict__ outA,
        const float* __restrict__ xB, const int* __restrict__ rpB,
        const int* __restrict__ csrB, int NB_,
        const float* __restrict__ wlB, const float* __restrict__ blB,
        const float* __restrict__ wrB, float* __restrict__ outB) {
    __shared__ float swl[64 * 64];
    __shared__ float swr[64 * 64];
    __shared__ float sagg[4 * 64];
    __shared__ float sx[4 * 64];
    int bA = NA / 4;
    if ((int)blockIdx.x < bA)
        gsage_body<FA>(xA, rpA, csrA, NA, wlA, blA, wrA, outA, blockIdx.x, swl, swr, sagg, sx);
    else
        gsage_body<FB>(xB, rpB, csrB, NB_, wlB, blB, wrB, outB, blockIdx.x - bA, swl, swr, sagg, sx);
}

// ---------------------------------------------------------------------------
// Fused QKV projection -> bf16 (Q pre-scaled), both graphs in one launch.
// ---------------------------------------------------------------------------
__global__ __launch_bounds__(256) void k_qkv2(
        const float* __restrict__ xA, int NA, const float* __restrict__ xB, int NB_,
        const float* __restrict__ amp_w, const float* __restrict__ amp_b,
        const float* __restrict__ apm_w, const float* __restrict__ apm_b, float qs,
        unsigned short* __restrict__ QA, unsigned short* __restrict__ KA, unsigned short* __restrict__ VA,
        unsigned short* __restrict__ QB, unsigned short* __restrict__ KB, unsigned short* __restrict__ VB) {
    __shared__ float sq[D * D], sk[D * D], sv[D * D], sx[16 * D];
    int bA = NA / 16;
    const float *x, *wq, *bq, *wk, *bk, *wv, *bv;
    unsigned short *oq, *ok, *ov;
    int blk;
    if ((int)blockIdx.x < bA) {
        x = xA; blk = blockIdx.x;
        wq = amp_w;        bq = amp_b;
        wk = apm_w + 4096; bk = apm_b + 64;
        wv = apm_w + 8192; bv = apm_b + 128;
        oq = QA; ok = KA; ov = VA;
    } else {
        x = xB; blk = blockIdx.x - bA;
        wq = apm_w;        bq = apm_b;
        wk = amp_w + 4096; bk = amp_b + 64;
        wv = amp_w + 8192; bv = amp_b + 128;
        oq = QB; ok = KB; ov = VB;
    }
    for (int i = threadIdx.x; i < D * D; i += 256) { sq[i] = wq[i]; sk[i] = wk[i]; sv[i] = wv[i]; }
    int rbase = blk * 16;
    for (int i = threadIdx.x; i < 16 * D; i += 256) sx[i] = x[(size_t)rbase * D + i];
    __syncthreads();
    int c = threadIdx.x & 63;
    int r0 = (threadIdx.x >> 6) * 4;
    for (int rr = 0; rr < 4; ++rr) {
        int r = r0 + rr;
        float aq = bq[c], ak = bk[c], av = bv[c];
        #pragma unroll 8
        for (int k = 0; k < D; ++k) {
            float xv = sx[r * D + k];
            aq += xv * sq[k * D + c];
            ak += xv * sk[k * D + c];
            av += xv * sv[k * D + c];
        }
        size_t o = (size_t)(rbase + r) * D + c;
        oq[o] = f2bf(aq * qs);
        ok[o] = f2bf(ak);
        ov[o] = f2bf(av);
    }
}

// ---------------------------------------------------------------------------
// V transpose [N,64] -> [65,N] bf16 (row 64 = ones for the l-column trick),
// with within-32-chunk key permutation pi(k): swap bit2<->bit3 of k&15, so the
// attn kernel's natural cvt_pk packing of scores IS the PV A-fragment.
// Both V buffers handled in one launch.
// ---------------------------------------------------------------------------
__global__ void k_transp2(const unsigned short* __restrict__ inM, unsigned short* __restrict__ outM, int Nm,
                          const unsigned short* __restrict__ inP, unsigned short* __restrict__ outP, int Np) {
    __shared__ unsigned short tile[64][72];
    int bm = Nm >> 6;
    const unsigned short* in; unsigned short* out; int N;
    int blk = blockIdx.x;
    if (blk < bm) { in = inM; out = outM; N = Nm; }
    else { blk -= bm; in = inP; out = outP; N = Np; }
    int t = threadIdx.x;
    int rbase = blk * 64;
    {
        int r = t >> 2, c0 = (t & 3) * 16;
        const uint4* src = (const uint4*)(in + (size_t)(rbase + r) * 64 + c0);
        uint4 a = src[0], b = src[1];
        *(uint4*)(&tile[r][c0]) = a;
        *(uint4*)(&tile[r][c0 + 8]) = b;
    }
    __syncthreads();
    {
        int c = t >> 2, r0 = (t & 3) * 16;
        union { uint2 v2[4]; unsigned short s[16]; } u;
        #pragma unroll
        for (int i = 0; i < 16; ++i) u.s[i] = tile[r0 + i][c];
        int key0 = rbase + r0;
        int kc = key0 & ~31;
        int b16 = key0 & 16;
        unsigned short* op = out + (size_t)c * N;
        const int gmap[4] = {0, 8, 4, 12};   // pi: group {0,1,2,3} -> pos {0,8,4,12}
        #pragma unroll
        for (int b = 0; b < 4; ++b)
            *(uint2*)(op + kc + b16 + gmap[b]) = u.v2[b];
    }
    if (t < 8) {
        uint4 ones;
        ones.x = ones.y = ones.z = ones.w = 0x3F803F80u;  // bf16 1.0 pairs
        *(uint4*)(out + (size_t)64 * N + rbase + t * 8) = ones;
    }
}

// ---------------------------------------------------------------------------
// Split-K flash attention, 32x32x16 MFMA (K = DH = 16, zero padding).
// One wave per (32-query tile, head, split). S^T = mfma(K, Q, -m):
// lane holds 16 biased scores of query lane&31; deferred-max (branch-only
// wave reduce); l accumulates in PV column 16 via the ones-row of Vt.
// PV A-frag = natural in-lane cvt_pk packing (Vt key-permuted to match).
// Both directions in one launch (blockIdx.y).
// ---------------------------------------------------------------------------
__global__ __launch_bounds__(256) void k_attn2(
        const unsigned short* __restrict__ QmB, const unsigned short* __restrict__ KpB,
        const unsigned short* __restrict__ VpT, int Nm, int Np, int lsm,
        float* __restrict__ poM, float* __restrict__ pmM, float* __restrict__ plM,
        const unsigned short* __restrict__ QpB, const unsigned short* __restrict__ KmB,
        const unsigned short* __restrict__ VmT, int lsp,
        float* __restrict__ poP, float* __restrict__ pmP, float* __restrict__ plP) {
    const unsigned short *Q, *K, *Vt;
    int Nq, Nk, ls;
    float *po, *pm, *pl;
    if (blockIdx.y == 0) { Q = QmB; K = KpB; Vt = VpT; Nq = Nm; Nk = Np; ls = lsm; po = poM; pm = pmM; pl = plM; }
    else                 { Q = QpB; K = KmB; Vt = VmT; Nq = Np; Nk = Nm; ls = lsp; po = poP; pm = pmP; pl = plP; }
    int nqt = Nq >> 5;
    if ((int)blockIdx.x >= (nqt << ls)) return;
    const int qt = blockIdx.x >> ls;
    const int split = blockIdx.x & ((1 << ls) - 1);
    const int kchunk = Nk >> ls;
    const int h = threadIdx.x >> 6;
    const int lane = threadIdx.x & 63;
    const int cq = lane & 31;
    const int half = lane >> 5;
    const int h16 = h * 16;

    // Q B-frag: col = query, k = dh
    bf16x8 qb = *(const bf16x8*)(Q + ((size_t)(qt * 32 + cq) * D + h16 + half * 8));
    // V row for this lane's output column: d<16 real, d==16 ones-row, d>16 dup
    int drow = (cq < 16) ? (h16 + cq) : (cq == 16 ? 64 : h16 + 15);
    const unsigned short* vbase = Vt + (size_t)drow * Nk;

    f32x16 o, mC;
    #pragma unroll
    for (int i = 0; i < 16; ++i) { o[i] = 0.f; mC[i] = 0.f; }
    float m = 0.f;
    bool first = true;

    const int kstart = split * kchunk;
    for (int kb = kstart; kb < kstart + kchunk; kb += 32) {
        bf16x8 ka = *(const bf16x8*)(K + ((size_t)(kb + cq) * D + h16 + half * 8));
        f32x16 s = __builtin_amdgcn_mfma_f32_32x32x16_bf16(ka, qb, mC, 0, 0, 0);
        float cm = s[0];
        #pragma unroll
        for (int i = 1; i < 16; ++i) cm = fmaxf(cm, s[i]);
        if (first || __any(cm > 8.f)) {
            float cw = cm;
            #pragma unroll
            for (int off = 1; off < 64; off <<= 1) cw = fmaxf(cw, __shfl_xor(cw, off));
            float nm = m + cw;
            if (!first) {
                nm = fmaxf(nm, m);
                float sc = exp2f(m - nm);
                #pragma unroll
                for (int i = 0; i < 16; ++i) o[i] *= sc;
            }
            float dl = nm - m;
            #pragma unroll
            for (int i = 0; i < 16; ++i) { s[i] -= dl; mC[i] = -nm; }
            m = nm;
            first = false;
        }
        float p[16];
        #pragma unroll
        for (int i = 0; i < 16; ++i) p[i] = exp2f(s[i]);
        union { unsigned u[4]; bf16x8 v; } f1, f2;
        f1.u[0] = pk_bf16(p[0], p[1]);   f1.u[1] = pk_bf16(p[2], p[3]);
        f1.u[2] = pk_bf16(p[4], p[5]);   f1.u[3] = pk_bf16(p[6], p[7]);
        f2.u[0] = pk_bf16(p[8], p[9]);   f2.u[1] = pk_bf16(p[10], p[11]);
        f2.u[2] = pk_bf16(p[12], p[13]); f2.u[3] = pk_bf16(p[14], p[15]);
        bf16x8 vb0 = *(const bf16x8*)(vbase + kb + half * 8);
        bf16x8 vb1 = *(const bf16x8*)(vbase + kb + 16 + half * 8);
        o = __builtin_amdgcn_mfma_f32_32x32x16_bf16(f1.v, vb0, o, 0, 0, 0);
        o = __builtin_amdgcn_mfma_f32_32x32x16_bf16(f2.v, vb1, o, 0, 0, 0);
    }

    size_t pbase = (size_t)split * Nq + qt * 32;
    if (half == 0)
        pm[(pbase + cq) * 4 + h] = m;
    if (cq == 16) {
        #pragma unroll
        for (int r = 0; r < 16; ++r) {
            int qr = (r & 3) + 8 * (r >> 2) + 4 * half;
            pl[(pbase + qr) * 4 + h] = o[r];
        }
    }
    if (cq < 16) {
        #pragma unroll
        for (int r = 0; r < 16; ++r) {
            int qr = (r & 3) + 8 * (r >> 2) + 4 * half;
            po[(pbase + qr) * 64 + h16 + cq] = o[r];
        }
    }
}

// ---------------------------------------------------------------------------
// Combine split-K partials + residual + pooling (both directions, one launch)
// ---------------------------------------------------------------------------
__global__ void k_comb2(
        const float* __restrict__ poM, const float* __restrict__ pmM, const float* __restrict__ plM,
        int nsM, int Nm, const float* __restrict__ residM, const int* __restrict__ batchM,
        const float* __restrict__ poP, const float* __restrict__ pmP, const float* __restrict__ plP,
        int nsP, int Np, const float* __restrict__ residP, const int* __restrict__ batchP,
        float* __restrict__ zsum, float* __restrict__ zcnt) {
    int idx = blockIdx.x * blockDim.x + threadIdx.x;
    const float *po, *pm, *pl, *resid;
    const int* batch;
    int ns, Nq, colOff, i;
    int mtot = Nm * 64;
    if (idx < mtot) {
        po = poM; pm = pmM; pl = plM; ns = nsM; Nq = Nm; resid = residM; batch = batchM; colOff = 0; i = idx;
    } else {
        i = idx - mtot;
        if (i >= Np * 64) return;
        po = poP; pm = pmP; pl = plP; ns = nsP; Nq = Np; resid = residP; batch = batchP; colOff = 64;
    }
    int q = i >> 6, d = i & 63, h = d >> 4;
    float M = -1e30f;
    for (int s = 0; s < ns; ++s)
        M = fmaxf(M, pm[((size_t)s * Nq + q) * 4 + h]);
    float O = 0.f, L = 0.f;
    for (int s = 0; s < ns; ++s) {
        float wgt = exp2f(pm[((size_t)s * Nq + q) * 4 + h] - M);
        O += po[((size_t)s * Nq + q) * 64 + d] * wgt;
        L += pl[((size_t)s * Nq + q) * 4 + h] * wgt;
    }
    float val = resid[i] + O / L;
    int b = batch[q];
    atomicAdd(&zsum[b * 128 + colOff + d], val);
    if (d == 0) atomicAdd(&zcnt[b * 2 + (colOff ? 1 : 0)], 1.0f);
}

// ---------------------------------------------------------------------------
// Head MLP: one wave per batch element
// ---------------------------------------------------------------------------
__global__ __launch_bounds__(256) void k_head2(
        const float* __restrict__ zsum, const float* __restrict__ zcnt,
        const float* __restrict__ fc1w, const float* __restrict__ fc1b,
        const float* __restrict__ fc2w, const float* __restrict__ fc2b,
        float* __restrict__ out) {
    int b = blockIdx.x * 4 + (threadIdx.x >> 6);
    int c = threadIdx.x & 63;
    float inv0 = 1.0f / fmaxf(zcnt[b * 2 + 0], 1.0f);
    float inv1 = 1.0f / fmaxf(zcnt[b * 2 + 1], 1.0f);
    float acc = fc1b[c];
    #pragma unroll 8
    for (int k = 0; k < 128; ++k) {
        float zv = zsum[b * 128 + k] * (k < 64 ? inv0 : inv1);
        acc += zv * fc1w[k * 64 + c];
    }
    float v = fmaxf(acc, 0.0f) * fc2w[c];
    #pragma unroll
    for (int off = 32; off > 0; off >>= 1) v += __shfl_xor(v, off);
    if (c == 0) out[b] = 1.0f / (1.0f + __expf(-(v + fc2b[0])));
}

// ---------------------------------------------------------------------------
extern "C" void kernel_launch(void* const* d_in, const int* in_sizes, int n_in,
                              void* d_out, int out_size, void* d_ws, size_t ws_size,
                              hipStream_t stream) {
    const float* x_mol  = (const float*)d_in[0];
    const float* x_prot = (const float*)d_in[1];
    const float* m1_wl = (const float*)d_in[2];
    const float* m1_bl = (const float*)d_in[3];
    const float* m1_wr = (const float*)d_in[4];
    const float* m2_wl = (const float*)d_in[5];
    const float* m2_bl = (const float*)d_in[6];
    const float* m2_wr = (const float*)d_in[7];
    const float* p1_wl = (const float*)d_in[8];
    const float* p1_bl = (const float*)d_in[9];
    const float* p1_wr = (const float*)d_in[10];
    const float* p2_wl = (const float*)d_in[11];
    const float* p2_bl = (const float*)d_in[12];
    const float* p2_wr = (const float*)d_in[13];
    const float* amp_w = (const float*)d_in[14];
    const float* amp_b = (const float*)d_in[15];
    const float* apm_w = (const float*)d_in[16];
    const float* apm_b = (const float*)d_in[17];
    const float* fc1_w = (const float*)d_in[18];
    const float* fc1_b = (const float*)d_in[19];
    const float* fc2_w = (const float*)d_in[20];
    const float* fc2_b = (const float*)d_in[21];
    const int* edge_mol  = (const int*)d_in[22];
    const int* edge_prot = (const int*)d_in[23];
    const int* batch_mol  = (const int*)d_in[24];
    const int* batch_prot = (const int*)d_in[25];
    float* out = (float*)d_out;

    const int N_MOL  = in_sizes[0] / 32;
    const int N_PROT = in_sizes[1] / 64;
    const int E_MOL  = in_sizes[22] / 2;
    const int E_PROT = in_sizes[23] / 2;

    // ---- workspace bump allocator ----
    char* base = (char*)d_ws;
    size_t off = 0;
    auto alloc = [&](size_t bytes) -> void* {
        void* p = base + off;
        off = (off + bytes + 255) & ~(size_t)255;
        return p;
    };
    float* h_mol1   = (float*)alloc((size_t)N_MOL * D * sizeof(float));
    float* h_mol2   = (float*)alloc((size_t)N_MOL * D * sizeof(float));
    float* h_prot1  = (float*)alloc((size_t)N_PROT * D * sizeof(float));
    float* h_prot2  = (float*)alloc((size_t)N_PROT * D * sizeof(float));
    float* zsum     = (float*)alloc((NB * 128 + NB * 2) * sizeof(float));
    float* zcnt     = zsum + NB * 128;
    unsigned short* Qm_b = (unsigned short*)alloc((size_t)N_MOL * D * 2);
    unsigned short* Km_b = (unsigned short*)alloc((size_t)N_MOL * D * 2);
    unsigned short* Vm_b = (unsigned short*)alloc((size_t)N_MOL * D * 2);
    unsigned short* Vm_t = (unsigned short*)alloc((size_t)N_MOL * (D + 1) * 2);
    unsigned short* Qp_b = (unsigned short*)alloc((size_t)N_PROT * D * 2);
    unsigned short* Kp_b = (unsigned short*)alloc((size_t)N_PROT * D * 2);
    unsigned short* Vp_b = (unsigned short*)alloc((size_t)N_PROT * D * 2);
    unsigned short* Vp_t = (unsigned short*)alloc((size_t)N_PROT * (D + 1) * 2);
    // CSR
    int* deg      = (int*)alloc(((size_t)N_MOL + N_PROT) * sizeof(int));
    int* deg_m    = deg;
    int* deg_p    = deg + N_MOL;
    int* rp_m     = (int*)alloc(((size_t)N_MOL + 1) * sizeof(int));
    int* cur_m    = (int*)alloc((size_t)N_MOL * sizeof(int));
    int* csr_m    = (int*)alloc((size_t)E_MOL * sizeof(int));
    int* rp_p     = (int*)alloc(((size_t)N_PROT + 1) * sizeof(int));
    int* cur_p    = (int*)alloc((size_t)N_PROT * sizeof(int));
    int* csr_p    = (int*)alloc((size_t)E_PROT * sizeof(int));

    // split-K factors (keys per split must be a multiple of 32)
    int nsm = 8; while (nsm > 1 && (N_PROT % (32 * nsm))) nsm >>= 1;  // mol queries prot keys
    int nsp = 4; while (nsp > 1 && (N_MOL % (32 * nsp)))  nsp >>= 1;  // prot queries mol keys
    int lsm = 31 - __builtin_clz(nsm);
    int lsp = 31 - __builtin_clz(nsp);
    float* poM = (float*)alloc((size_t)nsm * N_MOL * 64 * sizeof(float));
    float* pmM = (float*)alloc((size_t)nsm * N_MOL * 4 * sizeof(float));
    float* plM = (float*)alloc((size_t)nsm * N_MOL * 4 * sizeof(float));
    float* poP = (float*)alloc((size_t)nsp * N_PROT * 64 * sizeof(float));
    float* pmP = (float*)alloc((size_t)nsp * N_PROT * 4 * sizeof(float));
    float* plP = (float*)alloc((size_t)nsp * N_PROT * 4 * sizeof(float));

    const int BLK = 256;
    dim3 blk(BLK);
    const float QS = 0.25f * 1.4426950408889634f;  // 1/sqrt(DH) * log2(e)

    // ---- CSR build ----
    hipMemsetAsync(deg, 0, ((size_t)N_MOL + N_PROT) * sizeof(int), stream);
    hipMemsetAsync(zsum, 0, (NB * 128 + NB * 2) * sizeof(float), stream);
    int Etot = E_MOL + E_PROT;
    k_hist2<<<(Etot + BLK - 1) / BLK, blk, 0, stream>>>(edge_mol, E_MOL, edge_prot, E_PROT, deg_m, deg_p);
    k_scan2<<<2, blk, 0, stream>>>(deg_m, N_MOL, rp_m, cur_m, deg_p, N_PROT, rp_p, cur_p);
    k_scatter2<<<(Etot + BLK - 1) / BLK, blk, 0, stream>>>(edge_mol, E_MOL, cur_m, csr_m,
                                                           edge_prot, E_PROT, cur_p, csr_p);

    // ---- SAGE layers (mol + prot merged per layer) ----
    k_gsage2<32, 64><<<N_MOL / 4 + N_PROT / 4, blk, 0, stream>>>(
        x_mol,  rp_m, csr_m, N_MOL,  m1_wl, m1_bl, m1_wr, h_mol1,
        x_prot, rp_p, csr_p, N_PROT, p1_wl, p1_bl, p1_wr, h_prot1);
    k_gsage2<64, 64><<<N_MOL / 4 + N_PROT / 4, blk, 0, stream>>>(
        h_mol1,  rp_m, csr_m, N_MOL,  m2_wl, m2_bl, m2_wr, h_mol2,
        h_prot1, rp_p, csr_p, N_PROT, p2_wl, p2_bl, p2_wr, h_prot2);

    // ---- QKV projections (merged) ----
    k_qkv2<<<N_MOL / 16 + N_PROT / 16, blk, 0, stream>>>(
        h_mol2, N_MOL, h_prot2, N_PROT, amp_w, amp_b, apm_w, apm_b, QS,
        Qm_b, Km_b, Vm_b, Qp_b, Kp_b, Vp_b);

    // ---- V transposes (merged, permuted, + ones row) ----
    k_transp2<<<N_MOL / 64 + N_PROT / 64, blk, 0, stream>>>(Vm_b, Vm_t, N_MOL, Vp_b, Vp_t, N_PROT);

    // ---- split-K flash attention (both directions, one launch) ----
    int gxm = (N_MOL / 32) * nsm;
    int gxp = (N_PROT / 32) * nsp;
    int gx = gxm > gxp ? gxm : gxp;
    k_attn2<<<dim3(gx, 2), blk, 0, stream>>>(
        Qm_b, Kp_b, Vp_t, N_MOL, N_PROT, lsm, poM, pmM, plM,
        Qp_b, Km_b, Vm_t, lsp, poP, pmP, plP);

    // ---- combine + residual + pooling (merged) ----
    k_comb2<<<((N_MOL + N_PROT) * 64 + BLK - 1) / BLK, blk, 0, stream>>>(
        poM, pmM, plM, nsm, N_MOL, h_mol2, batch_mol,
        poP, pmP, plP, nsp, N_PROT, h_prot2, batch_prot,
        zsum, zcnt);

    // ---- head ----
    k_head2<<<16, blk, 0, stream>>>(zsum, zcnt, fc1_w, fc1_b, fc2_w, fc2_b, out);
}

// Round 9
// 206.313 us; speedup vs baseline: 10.7834x; 1.0915x over previous
//
#include <hip/hip_runtime.h>
#include <math.h>

#define D 64
#define NB 64

typedef __attribute__((ext_vector_type(8))) short bf16x8;
typedef __attribute__((ext_vector_type(4))) float f32x4;
typedef __attribute__((ext_vector_type(16))) float f32x16;

#define M3(a, b, c) fmaxf(fmaxf((a), (b)), (c))

__device__ __forceinline__ unsigned short f2bf(float f) {
    unsigned u = __float_as_uint(f);
    u += 0x7FFF + ((u >> 16) & 1);
    return (unsigned short)(u >> 16);
}
__device__ __forceinline__ unsigned pk_bf16(float lo, float hi) {
    unsigned r;
    asm("v_cvt_pk_bf16_f32 %0, %1, %2" : "=v"(r) : "v"(lo), "v"(hi));
    return r;
}
__device__ __forceinline__ float fexp2(float x) {
    float r;
    asm("v_exp_f32 %0, %1" : "=v"(r) : "v"(x));
    return r;
}

// ---------------------------------------------------------------------------
// Zero helper: deg[] (int) and zsum/zcnt (float) in one dispatch
// ---------------------------------------------------------------------------
__global__ void k_zero(int* __restrict__ deg, int ndeg, float* __restrict__ zs, int nz) {
    int i = blockIdx.x * blockDim.x + threadIdx.x;
    if (i < ndeg) deg[i] = 0;
    if (i < nz) zs[i] = 0.f;
}

// ---------------------------------------------------------------------------
// CSR build: histogram of dst degrees (both graphs, one launch)
// ---------------------------------------------------------------------------
__global__ void k_hist2(const int* __restrict__ em, int Em,
                        const int* __restrict__ ep, int Ep,
                        int* __restrict__ degm, int* __restrict__ degp) {
    int i = blockIdx.x * blockDim.x + threadIdx.x;
    if (i < Em) atomicAdd(&degm[em[Em + i]], 1);
    int j = i - Em;
    if (j >= 0 && j < Ep) atomicAdd(&degp[ep[Ep + j]], 1);
}

// ---------------------------------------------------------------------------
// CSR build: exclusive prefix sum (block 0 = mol, block 1 = prot)
// ---------------------------------------------------------------------------
__global__ __launch_bounds__(256) void k_scan2(
        const int* __restrict__ degm, int Nm, int* __restrict__ rpm, int* __restrict__ curm,
        const int* __restrict__ degp, int Np, int* __restrict__ rpp, int* __restrict__ curp) {
    __shared__ int sdeg[8192];
    __shared__ int chunk[256];
    const int* deg = blockIdx.x ? degp : degm;
    int N = blockIdx.x ? Np : Nm;
    int* rowptr = blockIdx.x ? rpp : rpm;
    int* cursor = blockIdx.x ? curp : curm;
    int t = threadIdx.x;
    for (int i = t; i < N; i += 256) sdeg[i] = deg[i];
    __syncthreads();
    int C = (N + 255) / 256;
    int start = t * C;
    int sum = 0;
    for (int i = 0; i < C; ++i)
        if (start + i < N) sum += sdeg[start + i];
    chunk[t] = sum;
    __syncthreads();
    for (int ofs = 1; ofs < 256; ofs <<= 1) {
        int v = (t >= ofs) ? chunk[t - ofs] : 0;
        __syncthreads();
        chunk[t] += v;
        __syncthreads();
    }
    int base = (t == 0) ? 0 : chunk[t - 1];
    for (int i = 0; i < C && start + i < N; ++i) {
        rowptr[start + i] = base;
        cursor[start + i] = base;
        base += sdeg[start + i];
    }
    if (t == 255) rowptr[N] = base;
}

// ---------------------------------------------------------------------------
// CSR build: scatter src indices (both graphs, one launch)
// ---------------------------------------------------------------------------
__global__ void k_scatter2(const int* __restrict__ em, int Em, int* __restrict__ curm,
                           int* __restrict__ csrm,
                           const int* __restrict__ ep, int Ep, int* __restrict__ curp,
                           int* __restrict__ csrp) {
    int i = blockIdx.x * blockDim.x + threadIdx.x;
    if (i < Em) {
        int s = em[i], d = em[Em + i];
        csrm[atomicAdd(&curm[d], 1)] = s;
    }
    int j = i - Em;
    if (j >= 0 && j < Ep) {
        int s = ep[j], d = ep[Ep + j];
        csrp[atomicAdd(&curp[d], 1)] = s;
    }
}

// ---------------------------------------------------------------------------
// Fused gather + SAGE linear body (one wave per row)
// ---------------------------------------------------------------------------
template<int FIN>
__device__ __forceinline__ void gsage_body(
        const float* __restrict__ x, const int* __restrict__ rowptr,
        const int* __restrict__ csr, int N,
        const float* __restrict__ wl, const float* __restrict__ bl,
        const float* __restrict__ wr, float* __restrict__ out,
        int blk, float* __restrict__ swl, float* __restrict__ swr,
        float* __restrict__ sagg, float* __restrict__ sx) {
    for (int i = threadIdx.x; i < FIN * D; i += 256) { swl[i] = wl[i]; swr[i] = wr[i]; }
    int w = threadIdx.x >> 6;
    int lane = threadIdx.x & 63;
    int r = blk * 4 + w;
    if (r < N) {
        int e0 = rowptr[r], e1 = rowptr[r + 1];
        float inv = 1.0f / fmaxf((float)(e1 - e0), 1.0f);
        if (FIN == 64) {
            float a0 = 0.f, a1 = 0.f, a2 = 0.f, a3 = 0.f;
            int e = e0;
            for (; e + 3 < e1; e += 4) {
                a0 += x[(size_t)csr[e] * FIN + lane];
                a1 += x[(size_t)csr[e + 1] * FIN + lane];
                a2 += x[(size_t)csr[e + 2] * FIN + lane];
                a3 += x[(size_t)csr[e + 3] * FIN + lane];
            }
            for (; e < e1; ++e) a0 += x[(size_t)csr[e] * FIN + lane];
            sagg[w * 64 + lane] = ((a0 + a1) + (a2 + a3)) * inv;
            sx[w * 64 + lane] = x[(size_t)r * FIN + lane];
        } else {
            int f = lane & 31, half = lane >> 5;
            float a = 0.f;
            for (int e = e0 + half; e < e1; e += 2)
                a += x[(size_t)csr[e] * FIN + f];
            a += __shfl_xor(a, 32);
            if (half == 0) {
                sagg[w * 64 + f] = a * inv;
                sx[w * 64 + f] = x[(size_t)r * FIN + f];
            }
        }
    }
    __syncthreads();
    if (r >= N) return;
    int c = lane;
    float acc = bl[c];
    #pragma unroll 8
    for (int k = 0; k < FIN; ++k) {
        acc += sagg[w * 64 + k] * swl[k * D + c];
        acc += sx[w * 64 + k] * swr[k * D + c];
    }
    out[(size_t)r * D + c] = fmaxf(acc, 0.0f);
}

template<int FA, int FB>
__global__ __launch_bounds__(256) void k_gsage2(
        const float* __restrict__ xA, const int* __restrict__ rpA,
        const int* __restrict__ csrA, int NA,
        const float* __restrict__ wlA, const float* __restrict__ blA,
        const float* __restrict__ wrA, float* __restrict__ outA,
        const float* __restrict__ xB, const int* __restrict__ rpB,
        const int* __restrict__ csrB, int NB_,
        const float* __restrict__ wlB, const float* __restrict__ blB,
        const float* __restrict__ wrB, float* __restrict__ outB) {
    __shared__ float swl[64 * 64];
    __shared__ float swr[64 * 64];
    __shared__ float sagg[4 * 64];
    __shared__ float sx[4 * 64];
    int bA = NA / 4;
    if ((int)blockIdx.x < bA)
        gsage_body<FA>(xA, rpA, csrA, NA, wlA, blA, wrA, outA, blockIdx.x, swl, swr, sagg, sx);
    else
        gsage_body<FB>(xB, rpB, csrB, NB_, wlB, blB, wrB, outB, blockIdx.x - bA, swl, swr, sagg, sx);
}

// ---------------------------------------------------------------------------
// Fused QKV projection -> bf16 (Q pre-scaled), both graphs in one launch.
// ---------------------------------------------------------------------------
__global__ __launch_bounds__(256) void k_qkv2(
        const float* __restrict__ xA, int NA, const float* __restrict__ xB, int NB_,
        const float* __restrict__ amp_w, const float* __restrict__ amp_b,
        const float* __restrict__ apm_w, const float* __restrict__ apm_b, float qs,
        unsigned short* __restrict__ QA, unsigned short* __restrict__ KA, unsigned short* __restrict__ VA,
        unsigned short* __restrict__ QB, unsigned short* __restrict__ KB, unsigned short* __restrict__ VB) {
    __shared__ float sq[D * D], sk[D * D], sv[D * D], sx[16 * D];
    int bA = NA / 16;
    const float *x, *wq, *bq, *wk, *bk, *wv, *bv;
    unsigned short *oq, *ok, *ov;
    int blk;
    if ((int)blockIdx.x < bA) {
        x = xA; blk = blockIdx.x;
        wq = amp_w;        bq = amp_b;
        wk = apm_w + 4096; bk = apm_b + 64;
        wv = apm_w + 8192; bv = apm_b + 128;
        oq = QA; ok = KA; ov = VA;
    } else {
        x = xB; blk = blockIdx.x - bA;
        wq = apm_w;        bq = apm_b;
        wk = amp_w + 4096; bk = amp_b + 64;
        wv = amp_w + 8192; bv = amp_b + 128;
        oq = QB; ok = KB; ov = VB;
    }
    for (int i = threadIdx.x; i < D * D; i += 256) { sq[i] = wq[i]; sk[i] = wk[i]; sv[i] = wv[i]; }
    int rbase = blk * 16;
    for (int i = threadIdx.x; i < 16 * D; i += 256) sx[i] = x[(size_t)rbase * D + i];
    __syncthreads();
    int c = threadIdx.x & 63;
    int r0 = (threadIdx.x >> 6) * 4;
    for (int rr = 0; rr < 4; ++rr) {
        int r = r0 + rr;
        float aq = bq[c], ak = bk[c], av = bv[c];
        #pragma unroll 8
        for (int k = 0; k < D; ++k) {
            float xv = sx[r * D + k];
            aq += xv * sq[k * D + c];
            ak += xv * sk[k * D + c];
            av += xv * sv[k * D + c];
        }
        size_t o = (size_t)(rbase + r) * D + c;
        oq[o] = f2bf(aq * qs);
        ok[o] = f2bf(ak);
        ov[o] = f2bf(av);
    }
}

// ---------------------------------------------------------------------------
// V transpose [N,64] -> [65,N] bf16 (row 64 = ones for the l-column trick),
// with within-32-chunk key permutation (swap bit2<->bit3) so the attn
// kernel's natural cvt_pk packing of scores IS the PV A-fragment.
// ---------------------------------------------------------------------------
__global__ void k_transp2(const unsigned short* __restrict__ inM, unsigned short* __restrict__ outM, int Nm,
                          const unsigned short* __restrict__ inP, unsigned short* __restrict__ outP, int Np) {
    __shared__ unsigned short tile[64][72];
    int bm = Nm >> 6;
    const unsigned short* in; unsigned short* out; int N;
    int blk = blockIdx.x;
    if (blk < bm) { in = inM; out = outM; N = Nm; }
    else { blk -= bm; in = inP; out = outP; N = Np; }
    int t = threadIdx.x;
    int rbase = blk * 64;
    {
        int r = t >> 2, c0 = (t & 3) * 16;
        const uint4* src = (const uint4*)(in + (size_t)(rbase + r) * 64 + c0);
        uint4 a = src[0], b = src[1];
        *(uint4*)(&tile[r][c0]) = a;
        *(uint4*)(&tile[r][c0 + 8]) = b;
    }
    __syncthreads();
    {
        int c = t >> 2, r0 = (t & 3) * 16;
        union { uint2 v2[4]; unsigned short s[16]; } u;
        #pragma unroll
        for (int i = 0; i < 16; ++i) u.s[i] = tile[r0 + i][c];
        int key0 = rbase + r0;
        int kc = key0 & ~31;
        int b16 = key0 & 16;
        unsigned short* op = out + (size_t)c * N;
        const int gmap[4] = {0, 8, 4, 12};
        #pragma unroll
        for (int b = 0; b < 4; ++b)
            *(uint2*)(op + kc + b16 + gmap[b]) = u.v2[b];
    }
    if (t < 8) {
        uint4 ones;
        ones.x = ones.y = ones.z = ones.w = 0x3F803F80u;  // bf16 1.0 pairs
        *(uint4*)(out + (size_t)64 * N + rbase + t * 8) = ones;
    }
}

// ---------------------------------------------------------------------------
// Split-K flash attention, 32x32x16 MFMA. 64 keys per iteration, peeled
// first chunk, deferred-max (bias via MFMA C operand), l via ones-row,
// permutation-free P->PV. Both directions one launch.
// ---------------------------------------------------------------------------
#define PVBLOCK(S, KB)                                                        \
    {                                                                         \
        float p[16];                                                          \
        _Pragma("unroll")                                                     \
        for (int i = 0; i < 16; ++i) p[i] = fexp2((S)[i]);                    \
        union { unsigned u[4]; bf16x8 v; } f1, f2;                            \
        f1.u[0] = pk_bf16(p[0], p[1]);   f1.u[1] = pk_bf16(p[2], p[3]);       \
        f1.u[2] = pk_bf16(p[4], p[5]);   f1.u[3] = pk_bf16(p[6], p[7]);       \
        f2.u[0] = pk_bf16(p[8], p[9]);   f2.u[1] = pk_bf16(p[10], p[11]);     \
        f2.u[2] = pk_bf16(p[12], p[13]); f2.u[3] = pk_bf16(p[14], p[15]);     \
        bf16x8 vb0 = *(const bf16x8*)(vbase + (KB) + half * 8);               \
        bf16x8 vb1 = *(const bf16x8*)(vbase + (KB) + 16 + half * 8);          \
        __builtin_amdgcn_s_setprio(1);                                        \
        o = __builtin_amdgcn_mfma_f32_32x32x16_bf16(f1.v, vb0, o, 0, 0, 0);   \
        o = __builtin_amdgcn_mfma_f32_32x32x16_bf16(f2.v, vb1, o, 0, 0, 0);   \
        __builtin_amdgcn_s_setprio(0);                                        \
    }

#define MAXTREE(cm, s0, s1)                                                   \
    {                                                                         \
        float c0 = M3(s0[0], s0[1], s0[2]);                                   \
        float c1 = M3(s0[3], s0[4], s0[5]);                                   \
        float c2 = M3(s0[6], s0[7], s0[8]);                                   \
        float c3 = M3(s0[9], s0[10], s0[11]);                                 \
        float c4 = M3(s0[12], s0[13], s0[14]);                                \
        float c5 = M3(s0[15], s1[0], s1[1]);                                  \
        float c6 = M3(s1[2], s1[3], s1[4]);                                   \
        float c7 = M3(s1[5], s1[6], s1[7]);                                   \
        float c8 = M3(s1[8], s1[9], s1[10]);                                  \
        float c9 = M3(s1[11], s1[12], s1[13]);                                \
        float ca = fmaxf(s1[14], s1[15]);                                     \
        float d0 = M3(c0, c1, c2);                                            \
        float d1 = M3(c3, c4, c5);                                            \
        float d2 = M3(c6, c7, c8);                                            \
        float d3 = M3(c9, ca, d0);                                            \
        cm = M3(d1, d2, d3);                                                  \
    }

__global__ __launch_bounds__(256) void k_attn2(
        const unsigned short* __restrict__ QmB, const unsigned short* __restrict__ KpB,
        const unsigned short* __restrict__ VpT, int Nm, int Np, int lsm,
        float* __restrict__ poM, float* __restrict__ pmM, float* __restrict__ plM,
        const unsigned short* __restrict__ QpB, const unsigned short* __restrict__ KmB,
        const unsigned short* __restrict__ VmT, int lsp,
        float* __restrict__ poP, float* __restrict__ pmP, float* __restrict__ plP) {
    const unsigned short *Q, *K, *Vt;
    int Nq, Nk, ls;
    float *po, *pm, *pl;
    if (blockIdx.y == 0) { Q = QmB; K = KpB; Vt = VpT; Nq = Nm; Nk = Np; ls = lsm; po = poM; pm = pmM; pl = plM; }
    else                 { Q = QpB; K = KmB; Vt = VmT; Nq = Np; Nk = Nm; ls = lsp; po = poP; pm = pmP; pl = plP; }
    int nqt = Nq >> 5;
    if ((int)blockIdx.x >= (nqt << ls)) return;
    const int qt = blockIdx.x >> ls;
    const int split = blockIdx.x & ((1 << ls) - 1);
    const int kchunk = Nk >> ls;       // multiple of 64
    const int h = threadIdx.x >> 6;
    const int lane = threadIdx.x & 63;
    const int cq = lane & 31;
    const int half = lane >> 5;
    const int h16 = h * 16;

    bf16x8 qb = *(const bf16x8*)(Q + ((size_t)(qt * 32 + cq) * D + h16 + half * 8));
    int drow = (cq < 16) ? (h16 + cq) : (cq == 16 ? 64 : h16 + 15);
    const unsigned short* vbase = Vt + (size_t)drow * Nk;

    f32x16 o, mC, zro;
    #pragma unroll
    for (int i = 0; i < 16; ++i) { o[i] = 0.f; zro[i] = 0.f; }
    float m;

    const int kstart = split * kchunk;
    // ---- peeled first 64 keys ----
    {
        const int kb = kstart;
        bf16x8 ka0 = *(const bf16x8*)(K + ((size_t)(kb + cq) * D + h16 + half * 8));
        bf16x8 ka1 = *(const bf16x8*)(K + ((size_t)(kb + 32 + cq) * D + h16 + half * 8));
        f32x16 s0 = __builtin_amdgcn_mfma_f32_32x32x16_bf16(ka0, qb, zro, 0, 0, 0);
        f32x16 s1 = __builtin_amdgcn_mfma_f32_32x32x16_bf16(ka1, qb, zro, 0, 0, 0);
        float cm;
        MAXTREE(cm, s0, s1);
        #pragma unroll
        for (int off = 1; off < 64; off <<= 1) cm = fmaxf(cm, __shfl_xor(cm, off));
        m = cm;
        #pragma unroll
        for (int i = 0; i < 16; ++i) { s0[i] -= m; s1[i] -= m; mC[i] = -m; }
        PVBLOCK(s0, kb)
        PVBLOCK(s1, kb + 32)
    }
    for (int kb = kstart + 64; kb < kstart + kchunk; kb += 64) {
        bf16x8 ka0 = *(const bf16x8*)(K + ((size_t)(kb + cq) * D + h16 + half * 8));
        bf16x8 ka1 = *(const bf16x8*)(K + ((size_t)(kb + 32 + cq) * D + h16 + half * 8));
        f32x16 s0 = __builtin_amdgcn_mfma_f32_32x32x16_bf16(ka0, qb, mC, 0, 0, 0);
        f32x16 s1 = __builtin_amdgcn_mfma_f32_32x32x16_bf16(ka1, qb, mC, 0, 0, 0);
        float cm;
        MAXTREE(cm, s0, s1);
        if (__any(cm > 8.f)) {            // deferred-max rescale (T13)
            float cw = cm;
            #pragma unroll
            for (int off = 1; off < 64; off <<= 1) cw = fmaxf(cw, __shfl_xor(cw, off));
            float nm = fmaxf(m + cw, m);
            float sc = fexp2(m - nm);
            #pragma unroll
            for (int i = 0; i < 16; ++i) o[i] *= sc;
            float dl = nm - m;
            #pragma unroll
            for (int i = 0; i < 16; ++i) { s0[i] -= dl; s1[i] -= dl; mC[i] = -nm; }
            m = nm;
        }
        PVBLOCK(s0, kb)
        PVBLOCK(s1, kb + 32)
    }

    size_t pbase = (size_t)split * Nq + qt * 32;
    if (half == 0)
        pm[(pbase + cq) * 4 + h] = m;
    if (cq == 16) {
        #pragma unroll
        for (int r = 0; r < 16; ++r) {
            int qr = (r & 3) + 8 * (r >> 2) + 4 * half;
            pl[(pbase + qr) * 4 + h] = o[r];
        }
    }
    if (cq < 16) {
        #pragma unroll
        for (int r = 0; r < 16; ++r) {
            int qr = (r & 3) + 8 * (r >> 2) + 4 * half;
            po[(pbase + qr) * 64 + h16 + cq] = o[r];
        }
    }
}

// ---------------------------------------------------------------------------
// Combine split-K partials + residual + pooling (both directions, one launch)
// ---------------------------------------------------------------------------
__global__ void k_comb2(
        const float* __restrict__ poM, const float* __restrict__ pmM, const float* __restrict__ plM,
        int nsM, int Nm, const float* __restrict__ residM, const int* __restrict__ batchM,
        const float* __restrict__ poP, const float* __restrict__ pmP, const float* __restrict__ plP,
        int nsP, int Np, const float* __restrict__ residP, const int* __restrict__ batchP,
        float* __restrict__ zsum, float* __restrict__ zcnt) {
    int idx = blockIdx.x * blockDim.x + threadIdx.x;
    const float *po, *pm, *pl, *resid;
    const int* batch;
    int ns, Nq, colOff, i;
    int mtot = Nm * 64;
    if (idx < mtot) {
        po = poM; pm = pmM; pl = plM; ns = nsM; Nq = Nm; resid = residM; batch = batchM; colOff = 0; i = idx;
    } else {
        i = idx - mtot;
        if (i >= Np * 64) return;
        po = poP; pm = pmP; pl = plP; ns = nsP; Nq = Np; resid = residP; batch = batchP; colOff = 64;
    }
    int q = i >> 6, d = i & 63, h = d >> 4;
    float M = -1e30f;
    for (int s = 0; s < ns; ++s)
        M = fmaxf(M, pm[((size_t)s * Nq + q) * 4 + h]);
    float O = 0.f, L = 0.f;
    for (int s = 0; s < ns; ++s) {
        float wgt = fexp2(pm[((size_t)s * Nq + q) * 4 + h] - M);
        O += po[((size_t)s * Nq + q) * 64 + d] * wgt;
        L += pl[((size_t)s * Nq + q) * 4 + h] * wgt;
    }
    float val = resid[i] + O / L;
    int b = batch[q];
    atomicAdd(&zsum[b * 128 + colOff + d], val);
    if (d == 0) atomicAdd(&zcnt[b * 2 + (colOff ? 1 : 0)], 1.0f);
}

// ---------------------------------------------------------------------------
// Head MLP: one wave per batch element
// ---------------------------------------------------------------------------
__global__ __launch_bounds__(256) void k_head2(
        const float* __restrict__ zsum, const float* __restrict__ zcnt,
        const float* __restrict__ fc1w, const float* __restrict__ fc1b,
        const float* __restrict__ fc2w, const float* __restrict__ fc2b,
        float* __restrict__ out) {
    int b = blockIdx.x * 4 + (threadIdx.x >> 6);
    int c = threadIdx.x & 63;
    float inv0 = 1.0f / fmaxf(zcnt[b * 2 + 0], 1.0f);
    float inv1 = 1.0f / fmaxf(zcnt[b * 2 + 1], 1.0f);
    float acc = fc1b[c];
    #pragma unroll 8
    for (int k = 0; k < 128; ++k) {
        float zv = zsum[b * 128 + k] * (k < 64 ? inv0 : inv1);
        acc += zv * fc1w[k * 64 + c];
    }
    float v = fmaxf(acc, 0.0f) * fc2w[c];
    #pragma unroll
    for (int off = 32; off > 0; off >>= 1) v += __shfl_xor(v, off);
    if (c == 0) out[b] = 1.0f / (1.0f + __expf(-(v + fc2b[0])));
}

// ---------------------------------------------------------------------------
extern "C" void kernel_launch(void* const* d_in, const int* in_sizes, int n_in,
                              void* d_out, int out_size, void* d_ws, size_t ws_size,
                              hipStream_t stream) {
    const float* x_mol  = (const float*)d_in[0];
    const float* x_prot = (const float*)d_in[1];
    const float* m1_wl = (const float*)d_in[2];
    const float* m1_bl = (const float*)d_in[3];
    const float* m1_wr = (const float*)d_in[4];
    const float* m2_wl = (const float*)d_in[5];
    const float* m2_bl = (const float*)d_in[6];
    const float* m2_wr = (const float*)d_in[7];
    const float* p1_wl = (const float*)d_in[8];
    const float* p1_bl = (const float*)d_in[9];
    const float* p1_wr = (const float*)d_in[10];
    const float* p2_wl = (const float*)d_in[11];
    const float* p2_bl = (const float*)d_in[12];
    const float* p2_wr = (const float*)d_in[13];
    const float* amp_w = (const float*)d_in[14];
    const float* amp_b = (const float*)d_in[15];
    const float* apm_w = (const float*)d_in[16];
    const float* apm_b = (const float*)d_in[17];
    const float* fc1_w = (const float*)d_in[18];
    const float* fc1_b = (const float*)d_in[19];
    const float* fc2_w = (const float*)d_in[20];
    const float* fc2_b = (const float*)d_in[21];
    const int* edge_mol  = (const int*)d_in[22];
    const int* edge_prot = (const int*)d_in[23];
    const int* batch_mol  = (const int*)d_in[24];
    const int* batch_prot = (const int*)d_in[25];
    float* out = (float*)d_out;

    const int N_MOL  = in_sizes[0] / 32;
    const int N_PROT = in_sizes[1] / 64;
    const int E_MOL  = in_sizes[22] / 2;
    const int E_PROT = in_sizes[23] / 2;

    // ---- workspace bump allocator ----
    char* base = (char*)d_ws;
    size_t off = 0;
    auto alloc = [&](size_t bytes) -> void* {
        void* p = base + off;
        off = (off + bytes + 255) & ~(size_t)255;
        return p;
    };
    float* h_mol1   = (float*)alloc((size_t)N_MOL * D * sizeof(float));
    float* h_mol2   = (float*)alloc((size_t)N_MOL * D * sizeof(float));
    float* h_prot1  = (float*)alloc((size_t)N_PROT * D * sizeof(float));
    float* h_prot2  = (float*)alloc((size_t)N_PROT * D * sizeof(float));
    float* zsum     = (float*)alloc((NB * 128 + NB * 2) * sizeof(float));
    float* zcnt     = zsum + NB * 128;
    unsigned short* Qm_b = (unsigned short*)alloc((size_t)N_MOL * D * 2);
    unsigned short* Km_b = (unsigned short*)alloc((size_t)N_MOL * D * 2);
    unsigned short* Vm_b = (unsigned short*)alloc((size_t)N_MOL * D * 2);
    unsigned short* Vm_t = (unsigned short*)alloc((size_t)N_MOL * (D + 1) * 2);
    unsigned short* Qp_b = (unsigned short*)alloc((size_t)N_PROT * D * 2);
    unsigned short* Kp_b = (unsigned short*)alloc((size_t)N_PROT * D * 2);
    unsigned short* Vp_b = (unsigned short*)alloc((size_t)N_PROT * D * 2);
    unsigned short* Vp_t = (unsigned short*)alloc((size_t)N_PROT * (D + 1) * 2);
    // CSR
    int* deg      = (int*)alloc(((size_t)N_MOL + N_PROT) * sizeof(int));
    int* deg_m    = deg;
    int* deg_p    = deg + N_MOL;
    int* rp_m     = (int*)alloc(((size_t)N_MOL + 1) * sizeof(int));
    int* cur_m    = (int*)alloc((size_t)N_MOL * sizeof(int));
    int* csr_m    = (int*)alloc((size_t)E_MOL * sizeof(int));
    int* rp_p     = (int*)alloc(((size_t)N_PROT + 1) * sizeof(int));
    int* cur_p    = (int*)alloc((size_t)N_PROT * sizeof(int));
    int* csr_p    = (int*)alloc((size_t)E_PROT * sizeof(int));

    // split-K factors (keys per split must be a multiple of 64)
    int nsm = 16; while (nsm > 1 && (N_PROT % (64 * nsm))) nsm >>= 1;  // mol queries prot keys
    int nsp = 4;  while (nsp > 1 && (N_MOL % (64 * nsp)))  nsp >>= 1;  // prot queries mol keys
    int lsm = 31 - __builtin_clz(nsm);
    int lsp = 31 - __builtin_clz(nsp);
    float* poM = (float*)alloc((size_t)nsm * N_MOL * 64 * sizeof(float));
    float* pmM = (float*)alloc((size_t)nsm * N_MOL * 4 * sizeof(float));
    float* plM = (float*)alloc((size_t)nsm * N_MOL * 4 * sizeof(float));
    float* poP = (float*)alloc((size_t)nsp * N_PROT * 64 * sizeof(float));
    float* pmP = (float*)alloc((size_t)nsp * N_PROT * 4 * sizeof(float));
    float* plP = (float*)alloc((size_t)nsp * N_PROT * 4 * sizeof(float));

    const int BLK = 256;
    dim3 blk(BLK);
    const float QS = 0.25f * 1.4426950408889634f;  // 1/sqrt(DH) * log2(e)

    // ---- zero deg + zsum/zcnt (one dispatch) ----
    {
        int ndeg = N_MOL + N_PROT;
        int nz = NB * 128 + NB * 2;
        int mx = ndeg > nz ? ndeg : nz;
        k_zero<<<(mx + BLK - 1) / BLK, blk, 0, stream>>>(deg, ndeg, zsum, nz);
    }
    int Etot = E_MOL + E_PROT;
    k_hist2<<<(Etot + BLK - 1) / BLK, blk, 0, stream>>>(edge_mol, E_MOL, edge_prot, E_PROT, deg_m, deg_p);
    k_scan2<<<2, blk, 0, stream>>>(deg_m, N_MOL, rp_m, cur_m, deg_p, N_PROT, rp_p, cur_p);
    k_scatter2<<<(Etot + BLK - 1) / BLK, blk, 0, stream>>>(edge_mol, E_MOL, cur_m, csr_m,
                                                           edge_prot, E_PROT, cur_p, csr_p);

    // ---- SAGE layers (mol + prot merged per layer) ----
    k_gsage2<32, 64><<<N_MOL / 4 + N_PROT / 4, blk, 0, stream>>>(
        x_mol,  rp_m, csr_m, N_MOL,  m1_wl, m1_bl, m1_wr, h_mol1,
        x_prot, rp_p, csr_p, N_PROT, p1_wl, p1_bl, p1_wr, h_prot1);
    k_gsage2<64, 64><<<N_MOL / 4 + N_PROT / 4, blk, 0, stream>>>(
        h_mol1,  rp_m, csr_m, N_MOL,  m2_wl, m2_bl, m2_wr, h_mol2,
        h_prot1, rp_p, csr_p, N_PROT, p2_wl, p2_bl, p2_wr, h_prot2);

    // ---- QKV projections (merged) ----
    k_qkv2<<<N_MOL / 16 + N_PROT / 16, blk, 0, stream>>>(
        h_mol2, N_MOL, h_prot2, N_PROT, amp_w, amp_b, apm_w, apm_b, QS,
        Qm_b, Km_b, Vm_b, Qp_b, Kp_b, Vp_b);

    // ---- V transposes (merged, permuted, + ones row) ----
    k_transp2<<<N_MOL / 64 + N_PROT / 64, blk, 0, stream>>>(Vm_b, Vm_t, N_MOL, Vp_b, Vp_t, N_PROT);

    // ---- split-K flash attention (both directions, one launch) ----
    int gxm = (N_MOL / 32) * nsm;
    int gxp = (N_PROT / 32) * nsp;
    int gx = gxm > gxp ? gxm : gxp;
    k_attn2<<<dim3(gx, 2), blk, 0, stream>>>(
        Qm_b, Kp_b, Vp_t, N_MOL, N_PROT, lsm, poM, pmM, plM,
        Qp_b, Km_b, Vm_t, lsp, poP, pmP, plP);

    // ---- combine + residual + pooling (merged) ----
    k_comb2<<<((N_MOL + N_PROT) * 64 + BLK - 1) / BLK, blk, 0, stream>>>(
        poM, pmM, plM, nsm, N_MOL, h_mol2, batch_mol,
        poP, pmP, plP, nsp, N_PROT, h_prot2, batch_prot,
        zsum, zcnt);

    // ---- head ----
    k_head2<<<16, blk, 0, stream>>>(zsum, zcnt, fc1_w, fc1_b, fc2_w, fc2_b, out);
}